// Round 9
// baseline (699.180 us; speedup 1.0000x reference)
//
#include <hip/hip_runtime.h>
#include <math.h>

#define N_NODES 50000
#define NUM_E   800000
#define E_TOT   (NUM_E + N_NODES)   // 850000 (self loops appended)
#define M_PAD   50048               // N_NODES rounded up to 128
#define NGRAPH  128
#define XS_COLS 576
#define EPS_BN  1e-5f

static inline int ceil_div(int a, int b) { return (a + b - 1) / b; }

typedef __attribute__((ext_vector_type(8))) short short8;
typedef __attribute__((ext_vector_type(4))) float f32x4;

__device__ __forceinline__ float bf2f(ushort u) {
    union { unsigned int i; float f; } v; v.i = ((unsigned int)u) << 16; return v.f;
}
__device__ __forceinline__ ushort f2bf(float f) {
    union { float f; unsigned int i; } v; v.f = f;
    unsigned int r = v.i + 0x7FFF + ((v.i >> 16) & 1);
    return (ushort)(r >> 16);
}
__device__ __forceinline__ float lrelu(float l) { return l > 0.f ? l : 0.2f * l; }

// ---------------- prep: 3 weight transposes ----------------
__global__ __launch_bounds__(256)
void prep_w(const float* __restrict__ W0, const float* __restrict__ W1,
            const float* __restrict__ W2,
            ushort* __restrict__ Wt0, ushort* __restrict__ Wt1, ushort* __restrict__ Wt2)
{
    int j = blockIdx.x * 256 + threadIdx.x;
    if (j < 256 * 128) { Wt0[j] = f2bf(W0[(size_t)(j % 128) * 256 + (j / 128)]); return; }
    j -= 256 * 128;
    if (j < 256 * 256) { Wt1[j] = f2bf(W1[(size_t)(j % 256) * 256 + (j / 256)]); return; }
    j -= 256 * 256;
    if (j < 64 * 256)  { Wt2[j] = f2bf(W2[(size_t)(j % 256) * 64 + (j / 256)]); }
}

// ---------------- wide bf16 MFMA GEMM (BM=128, BN=256=all cols, 8 waves) ----------------
// AMODE 0: A is fp32 x (convert in staging).  AMODE 2: A is bf16 ybuf; apply BN
// scale/shift (bnsc/bnsh, indexed by input column) during staging.
template<int AMODE>
__global__ __launch_bounds__(512)
void gemm_bf16_w(const void* __restrict__ Av, int lda,
                 const float* __restrict__ bnsc, const float* __restrict__ bnsh,
                 const ushort* __restrict__ Bt, int ldb,
                 ushort* __restrict__ C, int M, int K,
                 const float* __restrict__ asrc, const float* __restrict__ adst,
                 float* __restrict__ a_s, float* __restrict__ a_d)
{
    __shared__ __align__(16) ushort As[128][64 + 8];
    __shared__ __align__(16) ushort Bs[256][64 + 8];
    const int tid = threadIdx.x;
    const int lane = tid & 63;
    const int w = tid >> 6;
    const int m0 = blockIdx.x * 128;

    f32x4 acc[16] = {};

    for (int k0 = 0; k0 < K; k0 += 64) {
#pragma unroll
        for (int j = 0; j < 2; ++j) {
            int c = tid + j * 512;
            int r = c >> 3, cc = (c & 7) * 8;
            if constexpr (AMODE == 0) {
                const float* Af = (const float*)Av;
                int m = m0 + r; if (m >= M) m = M - 1;
                float4 v0 = *reinterpret_cast<const float4*>(Af + (size_t)m * lda + k0 + cc);
                float4 v1 = *reinterpret_cast<const float4*>(Af + (size_t)m * lda + k0 + cc + 4);
                short8 v = {(short)f2bf(v0.x), (short)f2bf(v0.y), (short)f2bf(v0.z), (short)f2bf(v0.w),
                            (short)f2bf(v1.x), (short)f2bf(v1.y), (short)f2bf(v1.z), (short)f2bf(v1.w)};
                *reinterpret_cast<short8*>(&As[r][cc]) = v;
            } else {
                const ushort* Ab = (const ushort*)Av;   // M_PAD rows allocated
                short8 y = *reinterpret_cast<const short8*>(Ab + (size_t)(m0 + r) * lda + k0 + cc);
                float4 sa = *reinterpret_cast<const float4*>(&bnsc[k0 + cc]);
                float4 sb = *reinterpret_cast<const float4*>(&bnsc[k0 + cc + 4]);
                float4 ha = *reinterpret_cast<const float4*>(&bnsh[k0 + cc]);
                float4 hb = *reinterpret_cast<const float4*>(&bnsh[k0 + cc + 4]);
                short8 v;
                v[0] = (short)f2bf(fmaf(bf2f((ushort)y[0]), sa.x, ha.x));
                v[1] = (short)f2bf(fmaf(bf2f((ushort)y[1]), sa.y, ha.y));
                v[2] = (short)f2bf(fmaf(bf2f((ushort)y[2]), sa.z, ha.z));
                v[3] = (short)f2bf(fmaf(bf2f((ushort)y[3]), sa.w, ha.w));
                v[4] = (short)f2bf(fmaf(bf2f((ushort)y[4]), sb.x, hb.x));
                v[5] = (short)f2bf(fmaf(bf2f((ushort)y[5]), sb.y, hb.y));
                v[6] = (short)f2bf(fmaf(bf2f((ushort)y[6]), sb.z, hb.z));
                v[7] = (short)f2bf(fmaf(bf2f((ushort)y[7]), sb.w, hb.w));
                *reinterpret_cast<short8*>(&As[r][cc]) = v;
            }
        }
#pragma unroll
        for (int j = 0; j < 4; ++j) {
            int c = tid + j * 512;
            int r = c >> 3, cc = (c & 7) * 8;
            short8 v = *reinterpret_cast<const short8*>(Bt + (size_t)r * ldb + k0 + cc);
            *reinterpret_cast<short8*>(&Bs[r][cc]) = v;
        }
        __syncthreads();
#pragma unroll
        for (int kc = 0; kc < 64; kc += 32) {
            short8 a = *reinterpret_cast<const short8*>(&As[w * 16 + (lane & 15)][kc + (lane >> 4) * 8]);
#pragma unroll
            for (int nf = 0; nf < 16; ++nf) {
                short8 b = *reinterpret_cast<const short8*>(&Bs[nf * 16 + (lane & 15)][kc + (lane >> 4) * 8]);
                acc[nf] = __builtin_amdgcn_mfma_f32_16x16x32_bf16(a, b, acc[nf], 0, 0, 0);
            }
        }
        __syncthreads();
    }

    const int mbase = m0 + w * 16 + (lane >> 4) * 4;
#pragma unroll
    for (int r = 0; r < 4; ++r) {
        int m = mbase + r;
        if (m < M) {
#pragma unroll
            for (int nf = 0; nf < 16; ++nf)
                C[(size_t)m * 256 + nf * 16 + (lane & 15)] = f2bf(acc[nf][r]);
        }
    }

    float asl[16], adl[16];
#pragma unroll
    for (int nf = 0; nf < 16; ++nf) {
        int col = nf * 16 + (lane & 15);
        asl[nf] = asrc[col];
        adl[nf] = adst[col];
    }
#pragma unroll
    for (int r = 0; r < 4; ++r) {
        float ps[4] = {0.f, 0.f, 0.f, 0.f};
        float pd[4] = {0.f, 0.f, 0.f, 0.f};
#pragma unroll
        for (int nf = 0; nf < 16; ++nf) {
            int h = nf >> 2;
            ps[h] = fmaf(acc[nf][r], asl[nf], ps[h]);
            pd[h] = fmaf(acc[nf][r], adl[nf], pd[h]);
        }
#pragma unroll
        for (int h = 0; h < 4; ++h) {
#pragma unroll
            for (int o = 1; o < 16; o <<= 1) {
                ps[h] += __shfl_xor(ps[h], o, 64);
                pd[h] += __shfl_xor(pd[h], o, 64);
            }
        }
        int m = mbase + r;
        if ((lane & 15) == 0 && m < M) {
#pragma unroll
            for (int h = 0; h < 4; ++h) {
                a_s[(size_t)m * 4 + h] = ps[h];
                a_d[(size_t)m * 4 + h] = pd[h];
            }
        }
    }
}

// ---------------- narrow GEMM for layer 2 (BN=64, H=1 epilogue, BN-staged A) ----------------
__global__ __launch_bounds__(256)
void gemm_bf16_n(const ushort* __restrict__ A, int lda,
                 const float* __restrict__ bnsc, const float* __restrict__ bnsh,
                 const ushort* __restrict__ Bt, int ldb,
                 ushort* __restrict__ C, int ldc, int M, int K,
                 const float* __restrict__ asrc, const float* __restrict__ adst,
                 float* __restrict__ a_s, float* __restrict__ a_d)
{
    constexpr int BM = 128, BN = 64, BK = 64;
    __shared__ __align__(16) ushort As[BM][BK + 8];
    __shared__ __align__(16) ushort Bs[BN][BK + 8];
    const int tid = threadIdx.x;
    const int lane = tid & 63;
    const int w = tid >> 6;
    const int m0 = blockIdx.x * BM;
    const int n0 = 0;

    f32x4 acc[2][4] = {};

    for (int k0 = 0; k0 < K; k0 += BK) {
#pragma unroll
        for (int j = 0; j < 4; ++j) {
            int c = tid + j * 256;
            int r = c >> 3, cc = (c & 7) * 8;
            short8 y = *reinterpret_cast<const short8*>(A + (size_t)(m0 + r) * lda + k0 + cc);
            float4 sa = *reinterpret_cast<const float4*>(&bnsc[k0 + cc]);
            float4 sb = *reinterpret_cast<const float4*>(&bnsc[k0 + cc + 4]);
            float4 ha = *reinterpret_cast<const float4*>(&bnsh[k0 + cc]);
            float4 hb = *reinterpret_cast<const float4*>(&bnsh[k0 + cc + 4]);
            short8 v;
            v[0] = (short)f2bf(fmaf(bf2f((ushort)y[0]), sa.x, ha.x));
            v[1] = (short)f2bf(fmaf(bf2f((ushort)y[1]), sa.y, ha.y));
            v[2] = (short)f2bf(fmaf(bf2f((ushort)y[2]), sa.z, ha.z));
            v[3] = (short)f2bf(fmaf(bf2f((ushort)y[3]), sa.w, ha.w));
            v[4] = (short)f2bf(fmaf(bf2f((ushort)y[4]), sb.x, hb.x));
            v[5] = (short)f2bf(fmaf(bf2f((ushort)y[5]), sb.y, hb.y));
            v[6] = (short)f2bf(fmaf(bf2f((ushort)y[6]), sb.z, hb.z));
            v[7] = (short)f2bf(fmaf(bf2f((ushort)y[7]), sb.w, hb.w));
            *reinterpret_cast<short8*>(&As[r][cc]) = v;
        }
#pragma unroll
        for (int j = 0; j < 2; ++j) {
            int c = tid + j * 256;
            int r = c >> 3, cc = (c & 7) * 8;
            short8 v = *reinterpret_cast<const short8*>(Bt + (size_t)(n0 + r) * ldb + k0 + cc);
            *reinterpret_cast<short8*>(&Bs[r][cc]) = v;
        }
        __syncthreads();
#pragma unroll
        for (int kc = 0; kc < BK; kc += 32) {
            short8 a[2], b[4];
#pragma unroll
            for (int mf = 0; mf < 2; ++mf)
                a[mf] = *reinterpret_cast<const short8*>(&As[w * 32 + mf * 16 + (lane & 15)][kc + (lane >> 4) * 8]);
#pragma unroll
            for (int nf = 0; nf < 4; ++nf)
                b[nf] = *reinterpret_cast<const short8*>(&Bs[nf * 16 + (lane & 15)][kc + (lane >> 4) * 8]);
#pragma unroll
            for (int mf = 0; mf < 2; ++mf)
#pragma unroll
                for (int nf = 0; nf < 4; ++nf)
                    acc[mf][nf] = __builtin_amdgcn_mfma_f32_16x16x32_bf16(a[mf], b[nf], acc[mf][nf], 0, 0, 0);
        }
        __syncthreads();
    }

#pragma unroll
    for (int mf = 0; mf < 2; ++mf) {
        int mbase = m0 + w * 32 + mf * 16 + (lane >> 4) * 4;
#pragma unroll
        for (int r = 0; r < 4; ++r) {
            int m = mbase + r;
            if (m < M) {
#pragma unroll
                for (int nf = 0; nf < 4; ++nf)
                    C[(size_t)m * ldc + n0 + nf * 16 + (lane & 15)] = f2bf(acc[mf][nf][r]);
            }
        }
    }

    float asl[4], adl[4];
#pragma unroll
    for (int nf = 0; nf < 4; ++nf) {
        int col = n0 + nf * 16 + (lane & 15);
        asl[nf] = asrc[col];
        adl[nf] = adst[col];
    }
#pragma unroll
    for (int mf = 0; mf < 2; ++mf) {
#pragma unroll
        for (int r = 0; r < 4; ++r) {
            float ps = 0.f, pd = 0.f;
#pragma unroll
            for (int nf = 0; nf < 4; ++nf) {
                ps = fmaf(acc[mf][nf][r], asl[nf], ps);
                pd = fmaf(acc[mf][nf][r], adl[nf], pd);
            }
#pragma unroll
            for (int o = 1; o < 16; o <<= 1) {
                ps += __shfl_xor(ps, o, 64);
                pd += __shfl_xor(pd, o, 64);
            }
            int m = m0 + w * 32 + mf * 16 + (lane >> 4) * 4 + r;
            if ((lane & 15) == 0 && m < M) {
                a_s[(size_t)m] = ps;
                a_d[(size_t)m] = pd;
            }
        }
    }
}

// ---------------- fused softmax + gather + BN-stats; y out in bf16 ----------------
template<int H, int C>
__global__ __launch_bounds__(256)
void gat_fused2(const int* __restrict__ offs, const int* __restrict__ ssrc,
                const float* __restrict__ a_s, const float* __restrict__ a_d,
                const ushort* __restrict__ hf, const float* __restrict__ bias,
                ushort* __restrict__ ybuf, float* __restrict__ bnsum)
{
    constexpr int V = (H * C) / 32;   // 8 (H=4) or 2 (H=1)
    constexpr int OF = H * C;         // 256 or 64
    __shared__ float alsh[4][2][64 * H];
    __shared__ int   ssh[4][2][64];
    __shared__ float ysh[8][OF];
    const int tid = threadIdx.x;
    const int lane = tid & 63;
    const int wv = tid >> 6;
    const int half = lane >> 5;
    const int ll = lane & 31;
    const int dl = wv * 2 + half;
    const int dst = blockIdx.x * 8 + dl;
    const int e0 = offs[dst], e1 = offs[dst + 1];
    const int deg = e1 - e0;
    const int hd = (ll * V) / C;

    float ad[H];
    if constexpr (H == 4) {
        float4 v = *reinterpret_cast<const float4*>(a_d + (size_t)dst * 4);
        ad[0] = v.x; ad[1] = v.y; ad[2] = v.z; ad[3] = v.w;
    } else ad[0] = a_d[dst];

    float acc[V];
#pragma unroll
    for (int k = 0; k < V; ++k) acc[k] = 0.f;

    if (deg <= 64) {
        const bool a0 = ll < deg;
        const bool a1 = 32 + ll < deg;
        const int s0 = ssrc[e0 + (a0 ? ll : 0)];
        const int s1 = ssrc[e0 + (a1 ? 32 + ll : 0)];
        float l0[H], l1[H], mx[H], sm[H];
        if constexpr (H == 4) {
            float4 v0 = *reinterpret_cast<const float4*>(a_s + (size_t)s0 * 4);
            float4 v1 = *reinterpret_cast<const float4*>(a_s + (size_t)s1 * 4);
            l0[0] = lrelu(v0.x + ad[0]); l0[1] = lrelu(v0.y + ad[1]);
            l0[2] = lrelu(v0.z + ad[2]); l0[3] = lrelu(v0.w + ad[3]);
            l1[0] = lrelu(v1.x + ad[0]); l1[1] = lrelu(v1.y + ad[1]);
            l1[2] = lrelu(v1.z + ad[2]); l1[3] = lrelu(v1.w + ad[3]);
        } else {
            l0[0] = lrelu(a_s[s0] + ad[0]);
            l1[0] = lrelu(a_s[s1] + ad[0]);
        }
#pragma unroll
        for (int t = 0; t < H; ++t) {
            float m = a0 ? l0[t] : -INFINITY;
            if (a1) m = fmaxf(m, l1[t]);
#pragma unroll
            for (int o = 1; o < 32; o <<= 1) m = fmaxf(m, __shfl_xor(m, o, 64));
            mx[t] = m;
            float s = (a0 ? __expf(l0[t] - m) : 0.f) + (a1 ? __expf(l1[t] - m) : 0.f);
#pragma unroll
            for (int o = 1; o < 32; o <<= 1) s += __shfl_xor(s, o, 64);
            sm[t] = s;
        }
        float inv[H];
#pragma unroll
        for (int t = 0; t < H; ++t) inv[t] = 1.f / (sm[t] + 1e-16f);
        if (a0) {
            ssh[wv][half][ll] = s0;
            if constexpr (H == 4) {
                float4 av = {__expf(l0[0] - mx[0]) * inv[0], __expf(l0[1] - mx[1]) * inv[1],
                             __expf(l0[2] - mx[2]) * inv[2], __expf(l0[3] - mx[3]) * inv[3]};
                *reinterpret_cast<float4*>(&alsh[wv][half][ll * 4]) = av;
            } else alsh[wv][half][ll] = __expf(l0[0] - mx[0]) * inv[0];
        }
        if (a1) {
            ssh[wv][half][32 + ll] = s1;
            if constexpr (H == 4) {
                float4 av = {__expf(l1[0] - mx[0]) * inv[0], __expf(l1[1] - mx[1]) * inv[1],
                             __expf(l1[2] - mx[2]) * inv[2], __expf(l1[3] - mx[3]) * inv[3]};
                *reinterpret_cast<float4*>(&alsh[wv][half][(32 + ll) * 4]) = av;
            } else alsh[wv][half][32 + ll] = __expf(l1[0] - mx[0]) * inv[0];
        }

        const ushort* hlane = hf + (size_t)ll * V;
        int j = 0;
        for (; j + 3 < deg; j += 4) {
            int sj[4]; float al[4];
#pragma unroll
            for (int k = 0; k < 4; ++k) {
                sj[k] = ssh[wv][half][j + k];
                al[k] = alsh[wv][half][(j + k) * H + hd];
            }
            if constexpr (V == 8) {
                short8 hv[4];
#pragma unroll
                for (int k = 0; k < 4; ++k)
                    hv[k] = *reinterpret_cast<const short8*>(hlane + (size_t)sj[k] * OF);
#pragma unroll
                for (int k = 0; k < 4; ++k)
#pragma unroll
                    for (int i = 0; i < 8; ++i)
                        acc[i] = fmaf(al[k], bf2f((ushort)hv[k][i]), acc[i]);
            } else {
                ushort2 hv[4];
#pragma unroll
                for (int k = 0; k < 4; ++k)
                    hv[k] = *reinterpret_cast<const ushort2*>(hlane + (size_t)sj[k] * OF);
#pragma unroll
                for (int k = 0; k < 4; ++k) {
                    acc[0] = fmaf(al[k], bf2f(hv[k].x), acc[0]);
                    acc[1] = fmaf(al[k], bf2f(hv[k].y), acc[1]);
                }
            }
        }
        for (; j < deg; ++j) {
            int sj = ssh[wv][half][j];
            float al = alsh[wv][half][j * H + hd];
            if constexpr (V == 8) {
                short8 hv = *reinterpret_cast<const short8*>(hlane + (size_t)sj * OF);
#pragma unroll
                for (int i = 0; i < 8; ++i)
                    acc[i] = fmaf(al, bf2f((ushort)hv[i]), acc[i]);
            } else {
                ushort2 hv = *reinterpret_cast<const ushort2*>(hlane + (size_t)sj * OF);
                acc[0] = fmaf(al, bf2f(hv.x), acc[0]);
                acc[1] = fmaf(al, bf2f(hv.y), acc[1]);
            }
        }
    } else {
        float mx[H], sm[H];
#pragma unroll
        for (int t = 0; t < H; ++t) mx[t] = -INFINITY;
        for (int e = e0 + ll; e < e1; e += 32) {
            int s = ssrc[e];
            float asv[H];
            if constexpr (H == 4) {
                float4 v = *reinterpret_cast<const float4*>(a_s + (size_t)s * 4);
                asv[0] = v.x; asv[1] = v.y; asv[2] = v.z; asv[3] = v.w;
            } else asv[0] = a_s[s];
#pragma unroll
            for (int t = 0; t < H; ++t) mx[t] = fmaxf(mx[t], lrelu(asv[t] + ad[t]));
        }
#pragma unroll
        for (int t = 0; t < H; ++t)
#pragma unroll
            for (int o = 1; o < 32; o <<= 1) mx[t] = fmaxf(mx[t], __shfl_xor(mx[t], o, 64));
#pragma unroll
        for (int t = 0; t < H; ++t) sm[t] = 0.f;
        for (int e = e0 + ll; e < e1; e += 32) {
            int s = ssrc[e];
            float asv[H];
            if constexpr (H == 4) {
                float4 v = *reinterpret_cast<const float4*>(a_s + (size_t)s * 4);
                asv[0] = v.x; asv[1] = v.y; asv[2] = v.z; asv[3] = v.w;
            } else asv[0] = a_s[s];
#pragma unroll
            for (int t = 0; t < H; ++t) sm[t] += __expf(lrelu(asv[t] + ad[t]) - mx[t]);
        }
#pragma unroll
        for (int t = 0; t < H; ++t)
#pragma unroll
            for (int o = 1; o < 32; o <<= 1) sm[t] += __shfl_xor(sm[t], o, 64);

        float mxl = mx[0], sml = sm[0], adl = ad[0];
#pragma unroll
        for (int t = 1; t < H; ++t) {
            mxl = (hd == t) ? mx[t] : mxl;
            sml = (hd == t) ? sm[t] : sml;
            adl = (hd == t) ? ad[t] : adl;
        }
        const float invl = 1.f / (sml + 1e-16f);
        const ushort* hlane = hf + (size_t)ll * V;
        for (int e = e0; e < e1; ++e) {
            int s0 = ssrc[e];
            float al0 = __expf(lrelu(a_s[(size_t)s0 * H + hd] + adl) - mxl) * invl;
            if constexpr (V == 8) {
                short8 hv = *reinterpret_cast<const short8*>(hlane + (size_t)s0 * OF);
#pragma unroll
                for (int i = 0; i < 8; ++i)
                    acc[i] = fmaf(al0, bf2f((ushort)hv[i]), acc[i]);
            } else {
                ushort2 hv = *reinterpret_cast<const ushort2*>(hlane + (size_t)s0 * OF);
                acc[0] = fmaf(al0, bf2f(hv.x), acc[0]);
                acc[1] = fmaf(al0, bf2f(hv.y), acc[1]);
            }
        }
    }

    // epilogue: + bias, ELU -> y (bf16 out + LDS stage for BN stats)
    float res[V];
#pragma unroll
    for (int i = 0; i < V; ++i) {
        float t = acc[i] + bias[ll * V + i];
        res[i] = t > 0.f ? t : (expf(t) - 1.f);
    }
    if constexpr (V == 8) {
        short8 yv = {(short)f2bf(res[0]), (short)f2bf(res[1]), (short)f2bf(res[2]), (short)f2bf(res[3]),
                     (short)f2bf(res[4]), (short)f2bf(res[5]), (short)f2bf(res[6]), (short)f2bf(res[7])};
        *reinterpret_cast<short8*>(&ybuf[(size_t)dst * OF + ll * 8]) = yv;
        *reinterpret_cast<f32x4*>(&ysh[dl][ll * 8 + 0]) = f32x4{res[0], res[1], res[2], res[3]};
        *reinterpret_cast<f32x4*>(&ysh[dl][ll * 8 + 4]) = f32x4{res[4], res[5], res[6], res[7]};
    } else {
        ushort2 yv = {f2bf(res[0]), f2bf(res[1])};
        *reinterpret_cast<ushort2*>(&ybuf[(size_t)dst * OF + ll * 2]) = yv;
        ysh[dl][ll * 2 + 0] = res[0];
        ysh[dl][ll * 2 + 1] = res[1];
    }
    __syncthreads();
    if (tid < OF) {
        float s = 0.f, s2 = 0.f;
#pragma unroll
        for (int d = 0; d < 8; ++d) {
            float v = ysh[d][tid];
            s += v;
            s2 = fmaf(v, v, s2);
        }
        int slot = blockIdx.x & 7;
        atomicAdd(&bnsum[(size_t)slot * 2 * OF + tid], s);
        atomicAdd(&bnsum[(size_t)slot * 2 * OF + OF + tid], s2);
    }
}

// ---------------- edge bucketing ----------------
__global__ void edge_count(const int* __restrict__ ei, int* __restrict__ counts)
{
    int i = blockIdx.x * blockDim.x + threadIdx.x;
    if (i >= E_TOT) return;
    int dst = (i < NUM_E) ? ei[NUM_E + i] : (i - NUM_E);
    atomicAdd(&counts[dst], 1);
}

__global__ void edge_scatter(const int* __restrict__ ei, int* __restrict__ cursor,
                             int* __restrict__ ssrc)
{
    int i = blockIdx.x * blockDim.x + threadIdx.x;
    if (i >= E_TOT) return;
    int src, dst;
    if (i < NUM_E) { src = ei[i]; dst = ei[NUM_E + i]; }
    else           { src = dst = i - NUM_E; }
    int pos = atomicAdd(&cursor[dst], 1);
    ssrc[pos] = src;
}

// ---------------- scan ----------------
__global__ void scan_block(const int* __restrict__ in, int n,
                           int* __restrict__ incl, int* __restrict__ bsum)
{
    __shared__ int sh[256];
    int tid = threadIdx.x;
    int i = blockIdx.x * 256 + tid;
    int v = (i < n) ? in[i] : 0;
    sh[tid] = v;
    __syncthreads();
    for (int o = 1; o < 256; o <<= 1) {
        int t = (tid >= o) ? sh[tid - o] : 0;
        __syncthreads();
        sh[tid] += t;
        __syncthreads();
    }
    if (i < n) incl[i] = sh[tid];
    if (tid == 255) bsum[blockIdx.x] = sh[255];
}

__global__ void scan_final(const int* __restrict__ incl, const int* __restrict__ in,
                           const int* __restrict__ bsum, int n,
                           int* __restrict__ offs, int* __restrict__ cursor)
{
    __shared__ int sh[256];
    const int tid = threadIdx.x;
    const int bi = blockIdx.x;
    sh[tid] = (tid < bi) ? bsum[tid] : 0;
    __syncthreads();
    for (int o = 128; o > 0; o >>= 1) {
        if (tid < o) sh[tid] += sh[tid + o];
        __syncthreads();
    }
    const int pref = sh[0];
    int i = bi * 256 + tid;
    if (i >= n) return;
    int excl = incl[i] - in[i] + pref;
    offs[i] = excl;
    cursor[i] = excl;
    if (i == n - 1) offs[n] = incl[i] + pref;
}

// ---------------- BN finalize: reduce 8 slots -> scale/shift; self-zero bnsum ----------------
template<int OF>
__global__ void bn_finalize(float* __restrict__ bnsum, const float* __restrict__ gamma,
                            const float* __restrict__ beta, float* __restrict__ ss)
{
    int c = threadIdx.x;
    if (c >= OF) return;
    float s = 0.f, s2 = 0.f;
#pragma unroll
    for (int slot = 0; slot < 8; ++slot) {
        s += bnsum[(size_t)slot * 2 * OF + c];
        s2 += bnsum[(size_t)slot * 2 * OF + OF + c];
        bnsum[(size_t)slot * 2 * OF + c] = 0.f;        // ready for next layer
        bnsum[(size_t)slot * 2 * OF + OF + c] = 0.f;
    }
    float mean = s / (float)N_NODES;
    float var = s2 / (float)N_NODES - mean * mean;
    float inv = rsqrtf(var + EPS_BN);
    float sc = inv * gamma[c];
    ss[c] = sc;
    ss[OF + c] = beta[c] - mean * sc;
}

// ---------------- BN apply from y(bf16) -> xs fp32 + fused pooling (4 cols/thread) ----------------
template<int OF>
__global__ __launch_bounds__(256)
void bn_apply_pool(const ushort* __restrict__ y, float* __restrict__ xs, int ldx,
                   const float* __restrict__ ss,
                   const int* __restrict__ batch, float* __restrict__ pool, int poff)
{
    constexpr int CG = OF / 4;        // col groups: 64 or 16
    constexpr int RS = 256 / CG;      // row lanes: 4 or 16
    const int tid = threadIdx.x;
    const int c = (tid % CG) * 4;
    const int rsub = tid / CG;
    const int r0 = blockIdx.x * 16;
    float4 sc = *reinterpret_cast<const float4*>(&ss[c]);
    float4 sh = *reinterpret_cast<const float4*>(&ss[OF + c]);
    float4 ps = {0.f, 0.f, 0.f, 0.f};
    int curg = batch[r0 + rsub];
#pragma unroll
    for (int i = 0; i < 16 / RS; ++i) {
        int r = r0 + rsub + i * RS;
        int g = batch[r];
        if (g != curg) {
            atomicAdd(&pool[(size_t)curg * XS_COLS + poff + c + 0], ps.x);
            atomicAdd(&pool[(size_t)curg * XS_COLS + poff + c + 1], ps.y);
            atomicAdd(&pool[(size_t)curg * XS_COLS + poff + c + 2], ps.z);
            atomicAdd(&pool[(size_t)curg * XS_COLS + poff + c + 3], ps.w);
            ps = {0.f, 0.f, 0.f, 0.f}; curg = g;
        }
        ushort4 hv = *reinterpret_cast<const ushort4*>(y + (size_t)r * OF + c);
        float4 v;
        v.x = fmaf(bf2f(hv.x), sc.x, sh.x);
        v.y = fmaf(bf2f(hv.y), sc.y, sh.y);
        v.z = fmaf(bf2f(hv.z), sc.z, sh.z);
        v.w = fmaf(bf2f(hv.w), sc.w, sh.w);
        *reinterpret_cast<float4*>(&xs[(size_t)r * ldx + c]) = v;
        ps.x += v.x; ps.y += v.y; ps.z += v.z; ps.w += v.w;
    }
    atomicAdd(&pool[(size_t)curg * XS_COLS + poff + c + 0], ps.x);
    atomicAdd(&pool[(size_t)curg * XS_COLS + poff + c + 1], ps.y);
    atomicAdd(&pool[(size_t)curg * XS_COLS + poff + c + 2], ps.z);
    atomicAdd(&pool[(size_t)curg * XS_COLS + poff + c + 3], ps.w);
}

extern "C" void kernel_launch(void* const* d_in, const int* in_sizes, int n_in,
                              void* d_out, int out_size, void* d_ws, size_t ws_size,
                              hipStream_t stream)
{
    const float* x     = (const float*)d_in[0];
    const int*   ei    = (const int*)d_in[1];
    const int*   batch = (const int*)d_in[2];
    const float* W[3]    = {(const float*)d_in[3],  (const float*)d_in[9],  (const float*)d_in[15]};
    const float* asrc[3] = {(const float*)d_in[4],  (const float*)d_in[10], (const float*)d_in[16]};
    const float* adst[3] = {(const float*)d_in[5],  (const float*)d_in[11], (const float*)d_in[17]};
    const float* bia[3]  = {(const float*)d_in[6],  (const float*)d_in[12], (const float*)d_in[18]};
    const float* gam[3]  = {(const float*)d_in[7],  (const float*)d_in[13], (const float*)d_in[19]};
    const float* bet[3]  = {(const float*)d_in[8],  (const float*)d_in[14], (const float*)d_in[20]};

    char* wp = (char*)d_ws;
    auto alloc = [&](size_t bytes) -> void* {
        void* p = (void*)wp;
        wp += (bytes + 255) & ~(size_t)255;
        return p;
    };
    ushort* hbf   = (ushort*)alloc((size_t)N_NODES * 256 * 2);
    ushort* ybuf  = (ushort*)alloc((size_t)M_PAD * 256 * 2);   // M_PAD rows: GEMM reads need no clamp
    float*  a_s   = (float*)alloc((size_t)N_NODES * 4 * 4);
    float*  a_d   = (float*)alloc((size_t)N_NODES * 4 * 4);
    int*    counts = (int*)alloc((size_t)N_NODES * 4);
    int*    offs   = (int*)alloc((size_t)(N_NODES + 1) * 4);
    int*    cursor = (int*)alloc((size_t)N_NODES * 4);
    int*    incl   = (int*)alloc((size_t)N_NODES * 4);
    int*    bsums  = (int*)alloc(1024);
    int*    ssrc   = (int*)alloc((size_t)E_TOT * 4);
    float*  bnsum  = (float*)alloc((size_t)8 * 2 * 256 * 4);
    float*  bnss   = (float*)alloc(2 * 256 * 4);
    ushort* Wt0    = (ushort*)alloc(256 * 128 * 2);
    ushort* Wt1    = (ushort*)alloc(256 * 256 * 2);
    ushort* Wt2    = (ushort*)alloc(64 * 256 * 2);

    float* pool = (float*)d_out;                    // [128, 576]
    float* xs   = pool + (size_t)NGRAPH * XS_COLS;  // [50000, 576]

    // ---- setup ----
    hipMemsetAsync(counts, 0, (size_t)N_NODES * 4, stream);
    hipMemsetAsync(pool, 0, (size_t)NGRAPH * XS_COLS * 4, stream);
    hipMemsetAsync(bnsum, 0, (size_t)8 * 2 * 256 * 4, stream);   // finalize self-zeroes thereafter
    edge_count<<<ceil_div(E_TOT, 256), 256, 0, stream>>>(ei, counts);
    const int NSB = ceil_div(N_NODES, 256);
    scan_block<<<NSB, 256, 0, stream>>>(counts, N_NODES, incl, bsums);
    scan_final<<<NSB, 256, 0, stream>>>(incl, counts, bsums, N_NODES, offs, cursor);
    edge_scatter<<<ceil_div(E_TOT, 256), 256, 0, stream>>>(ei, cursor, ssrc);
    const int PREP_ITEMS = 256 * 128 + 256 * 256 + 64 * 256;
    prep_w<<<ceil_div(PREP_ITEMS, 256), 256, 0, stream>>>(W[0], W[1], W[2], Wt0, Wt1, Wt2);

    const int NW2 = ceil_div(N_NODES, 8);   // 6250 (exact)
    const int NMB = ceil_div(N_NODES, 128);
    const int NBA = N_NODES / 16;           // 3125 (exact)

    // ---------------- layer 0: 128 -> 4x64 concat (256) ----------------
    {
        gemm_bf16_w<0><<<NMB, 512, 0, stream>>>(x, 128, nullptr, nullptr, Wt0, 128, hbf, N_NODES, 128,
                                                asrc[0], adst[0], a_s, a_d);
        gat_fused2<4, 64><<<NW2, 256, 0, stream>>>(offs, ssrc, a_s, a_d, hbf, bia[0], ybuf, bnsum);
        bn_finalize<256><<<1, 256, 0, stream>>>(bnsum, gam[0], bet[0], bnss);
        bn_apply_pool<256><<<NBA, 256, 0, stream>>>(ybuf, xs + 0, XS_COLS, bnss, batch, pool, 0);
    }
    // ---------------- layer 1: 256 -> 4x64 concat (256); BN applied in GEMM staging ----------------
    {
        gemm_bf16_w<2><<<NMB, 512, 0, stream>>>(ybuf, 256, bnss, bnss + 256, Wt1, 256, hbf, N_NODES, 256,
                                                asrc[1], adst[1], a_s, a_d);
        gat_fused2<4, 64><<<NW2, 256, 0, stream>>>(offs, ssrc, a_s, a_d, hbf, bia[1], ybuf, bnsum);
        bn_finalize<256><<<1, 256, 0, stream>>>(bnsum, gam[1], bet[1], bnss);
        bn_apply_pool<256><<<NBA, 256, 0, stream>>>(ybuf, xs + 256, XS_COLS, bnss, batch, pool, 256);
    }
    // ---------------- layer 2: 256 -> 1x64; BN applied in GEMM staging ----------------
    {
        gemm_bf16_n<<<NMB, 256, 0, stream>>>(ybuf, 256, bnss, bnss + 256, Wt2, 256, hbf, 64, N_NODES, 256,
                                             asrc[2], adst[2], a_s, a_d);
        gat_fused2<1, 64><<<NW2, 256, 0, stream>>>(offs, ssrc, a_s, a_d, hbf, bia[2], ybuf, bnsum);
        bn_finalize<64><<<1, 64, 0, stream>>>(bnsum, gam[2], bet[2], bnss);
        bn_apply_pool<64><<<NBA, 256, 0, stream>>>(ybuf, xs + 512, XS_COLS, bnss, batch, pool, 512);
    }
}

// Round 10
// 472.401 us; speedup vs baseline: 1.4801x; 1.4801x over previous
//
#include <hip/hip_runtime.h>
#include <math.h>

#define N_NODES 50000
#define NUM_E   800000
#define E_TOT   (NUM_E + N_NODES)   // 850000 (self loops appended)
#define M_PAD   50048               // N_NODES rounded up to 128
#define NGRAPH  128
#define XS_COLS 576
#define EPS_BN  1e-5f

static inline int ceil_div(int a, int b) { return (a + b - 1) / b; }

typedef __attribute__((ext_vector_type(8))) short short8;
typedef __attribute__((ext_vector_type(4))) float f32x4;

__device__ __forceinline__ float bf2f(ushort u) {
    union { unsigned int i; float f; } v; v.i = ((unsigned int)u) << 16; return v.f;
}
__device__ __forceinline__ ushort f2bf(float f) {
    union { float f; unsigned int i; } v; v.f = f;
    unsigned int r = v.i + 0x7FFF + ((v.i >> 16) & 1);
    return (ushort)(r >> 16);
}
__device__ __forceinline__ float lrelu(float l) { return l > 0.f ? l : 0.2f * l; }

// ---------------- prep: 3 weight transposes ----------------
__global__ __launch_bounds__(256)
void prep_w(const float* __restrict__ W0, const float* __restrict__ W1,
            const float* __restrict__ W2,
            ushort* __restrict__ Wt0, ushort* __restrict__ Wt1, ushort* __restrict__ Wt2)
{
    int j = blockIdx.x * 256 + threadIdx.x;
    if (j < 256 * 128) { Wt0[j] = f2bf(W0[(size_t)(j % 128) * 256 + (j / 128)]); return; }
    j -= 256 * 128;
    if (j < 256 * 256) { Wt1[j] = f2bf(W1[(size_t)(j % 256) * 256 + (j / 256)]); return; }
    j -= 256 * 256;
    if (j < 64 * 256)  { Wt2[j] = f2bf(W2[(size_t)(j % 256) * 64 + (j / 256)]); }
}

// ---------------- graph row ranges from SORTED batch ----------------
__global__ void graph_bounds(const int* __restrict__ batch, int* __restrict__ goffs)
{
    int i = blockIdx.x * 256 + threadIdx.x;
    if (i >= N_NODES) return;
    int b = batch[i];
    int prev = (i == 0) ? -1 : batch[i - 1];
    for (int g = prev + 1; g <= b; ++g) goffs[g] = i;
    if (i == N_NODES - 1)
        for (int g = b + 1; g <= NGRAPH; ++g) goffs[g] = N_NODES;
}

// ---------------- wide bf16 MFMA GEMM (BM=128, BN=256, 8 waves) ----------------
// AMODE 0: A fp32 (convert in staging).  AMODE 2: A bf16 ybuf + BN scale/shift in staging.
template<int AMODE>
__global__ __launch_bounds__(512)
void gemm_bf16_w(const void* __restrict__ Av, int lda,
                 const float* __restrict__ bnsc, const float* __restrict__ bnsh,
                 const ushort* __restrict__ Bt, int ldb,
                 ushort* __restrict__ C, int M, int K,
                 const float* __restrict__ asrc, const float* __restrict__ adst,
                 float* __restrict__ a_s, float* __restrict__ a_d)
{
    __shared__ __align__(16) ushort As[128][64 + 8];
    __shared__ __align__(16) ushort Bs[256][64 + 8];
    const int tid = threadIdx.x;
    const int lane = tid & 63;
    const int w = tid >> 6;
    const int m0 = blockIdx.x * 128;

    f32x4 acc[16] = {};

    for (int k0 = 0; k0 < K; k0 += 64) {
#pragma unroll
        for (int j = 0; j < 2; ++j) {
            int c = tid + j * 512;
            int r = c >> 3, cc = (c & 7) * 8;
            if constexpr (AMODE == 0) {
                const float* Af = (const float*)Av;
                int m = m0 + r; if (m >= M) m = M - 1;
                float4 v0 = *reinterpret_cast<const float4*>(Af + (size_t)m * lda + k0 + cc);
                float4 v1 = *reinterpret_cast<const float4*>(Af + (size_t)m * lda + k0 + cc + 4);
                short8 v = {(short)f2bf(v0.x), (short)f2bf(v0.y), (short)f2bf(v0.z), (short)f2bf(v0.w),
                            (short)f2bf(v1.x), (short)f2bf(v1.y), (short)f2bf(v1.z), (short)f2bf(v1.w)};
                *reinterpret_cast<short8*>(&As[r][cc]) = v;
            } else {
                const ushort* Ab = (const ushort*)Av;   // M_PAD rows allocated
                short8 y = *reinterpret_cast<const short8*>(Ab + (size_t)(m0 + r) * lda + k0 + cc);
                float4 sa = *reinterpret_cast<const float4*>(&bnsc[k0 + cc]);
                float4 sb = *reinterpret_cast<const float4*>(&bnsc[k0 + cc + 4]);
                float4 ha = *reinterpret_cast<const float4*>(&bnsh[k0 + cc]);
                float4 hb = *reinterpret_cast<const float4*>(&bnsh[k0 + cc + 4]);
                short8 v;
                v[0] = (short)f2bf(fmaf(bf2f((ushort)y[0]), sa.x, ha.x));
                v[1] = (short)f2bf(fmaf(bf2f((ushort)y[1]), sa.y, ha.y));
                v[2] = (short)f2bf(fmaf(bf2f((ushort)y[2]), sa.z, ha.z));
                v[3] = (short)f2bf(fmaf(bf2f((ushort)y[3]), sa.w, ha.w));
                v[4] = (short)f2bf(fmaf(bf2f((ushort)y[4]), sb.x, hb.x));
                v[5] = (short)f2bf(fmaf(bf2f((ushort)y[5]), sb.y, hb.y));
                v[6] = (short)f2bf(fmaf(bf2f((ushort)y[6]), sb.z, hb.z));
                v[7] = (short)f2bf(fmaf(bf2f((ushort)y[7]), sb.w, hb.w));
                *reinterpret_cast<short8*>(&As[r][cc]) = v;
            }
        }
#pragma unroll
        for (int j = 0; j < 4; ++j) {
            int c = tid + j * 512;
            int r = c >> 3, cc = (c & 7) * 8;
            short8 v = *reinterpret_cast<const short8*>(Bt + (size_t)r * ldb + k0 + cc);
            *reinterpret_cast<short8*>(&Bs[r][cc]) = v;
        }
        __syncthreads();
#pragma unroll
        for (int kc = 0; kc < 64; kc += 32) {
            short8 a = *reinterpret_cast<const short8*>(&As[w * 16 + (lane & 15)][kc + (lane >> 4) * 8]);
#pragma unroll
            for (int nf = 0; nf < 16; ++nf) {
                short8 b = *reinterpret_cast<const short8*>(&Bs[nf * 16 + (lane & 15)][kc + (lane >> 4) * 8]);
                acc[nf] = __builtin_amdgcn_mfma_f32_16x16x32_bf16(a, b, acc[nf], 0, 0, 0);
            }
        }
        __syncthreads();
    }

    const int mbase = m0 + w * 16 + (lane >> 4) * 4;
#pragma unroll
    for (int r = 0; r < 4; ++r) {
        int m = mbase + r;
        if (m < M) {
#pragma unroll
            for (int nf = 0; nf < 16; ++nf)
                C[(size_t)m * 256 + nf * 16 + (lane & 15)] = f2bf(acc[nf][r]);
        }
    }

    float asl[16], adl[16];
#pragma unroll
    for (int nf = 0; nf < 16; ++nf) {
        int col = nf * 16 + (lane & 15);
        asl[nf] = asrc[col];
        adl[nf] = adst[col];
    }
#pragma unroll
    for (int r = 0; r < 4; ++r) {
        float ps[4] = {0.f, 0.f, 0.f, 0.f};
        float pd[4] = {0.f, 0.f, 0.f, 0.f};
#pragma unroll
        for (int nf = 0; nf < 16; ++nf) {
            int h = nf >> 2;
            ps[h] = fmaf(acc[nf][r], asl[nf], ps[h]);
            pd[h] = fmaf(acc[nf][r], adl[nf], pd[h]);
        }
#pragma unroll
        for (int h = 0; h < 4; ++h) {
#pragma unroll
            for (int o = 1; o < 16; o <<= 1) {
                ps[h] += __shfl_xor(ps[h], o, 64);
                pd[h] += __shfl_xor(pd[h], o, 64);
            }
        }
        int m = mbase + r;
        if ((lane & 15) == 0 && m < M) {
#pragma unroll
            for (int h = 0; h < 4; ++h) {
                a_s[(size_t)m * 4 + h] = ps[h];
                a_d[(size_t)m * 4 + h] = pd[h];
            }
        }
    }
}

// ---------------- narrow GEMM for layer 2 (BN=64, H=1 epilogue, BN-staged A) ----------------
__global__ __launch_bounds__(256)
void gemm_bf16_n(const ushort* __restrict__ A, int lda,
                 const float* __restrict__ bnsc, const float* __restrict__ bnsh,
                 const ushort* __restrict__ Bt, int ldb,
                 ushort* __restrict__ C, int ldc, int M, int K,
                 const float* __restrict__ asrc, const float* __restrict__ adst,
                 float* __restrict__ a_s, float* __restrict__ a_d)
{
    constexpr int BM = 128, BN = 64, BK = 64;
    __shared__ __align__(16) ushort As[BM][BK + 8];
    __shared__ __align__(16) ushort Bs[BN][BK + 8];
    const int tid = threadIdx.x;
    const int lane = tid & 63;
    const int w = tid >> 6;
    const int m0 = blockIdx.x * BM;

    f32x4 acc[2][4] = {};

    for (int k0 = 0; k0 < K; k0 += BK) {
#pragma unroll
        for (int j = 0; j < 4; ++j) {
            int c = tid + j * 256;
            int r = c >> 3, cc = (c & 7) * 8;
            short8 y = *reinterpret_cast<const short8*>(A + (size_t)(m0 + r) * lda + k0 + cc);
            float4 sa = *reinterpret_cast<const float4*>(&bnsc[k0 + cc]);
            float4 sb = *reinterpret_cast<const float4*>(&bnsc[k0 + cc + 4]);
            float4 ha = *reinterpret_cast<const float4*>(&bnsh[k0 + cc]);
            float4 hb = *reinterpret_cast<const float4*>(&bnsh[k0 + cc + 4]);
            short8 v;
            v[0] = (short)f2bf(fmaf(bf2f((ushort)y[0]), sa.x, ha.x));
            v[1] = (short)f2bf(fmaf(bf2f((ushort)y[1]), sa.y, ha.y));
            v[2] = (short)f2bf(fmaf(bf2f((ushort)y[2]), sa.z, ha.z));
            v[3] = (short)f2bf(fmaf(bf2f((ushort)y[3]), sa.w, ha.w));
            v[4] = (short)f2bf(fmaf(bf2f((ushort)y[4]), sb.x, hb.x));
            v[5] = (short)f2bf(fmaf(bf2f((ushort)y[5]), sb.y, hb.y));
            v[6] = (short)f2bf(fmaf(bf2f((ushort)y[6]), sb.z, hb.z));
            v[7] = (short)f2bf(fmaf(bf2f((ushort)y[7]), sb.w, hb.w));
            *reinterpret_cast<short8*>(&As[r][cc]) = v;
        }
#pragma unroll
        for (int j = 0; j < 2; ++j) {
            int c = tid + j * 256;
            int r = c >> 3, cc = (c & 7) * 8;
            short8 v = *reinterpret_cast<const short8*>(Bt + (size_t)r * ldb + k0 + cc);
            *reinterpret_cast<short8*>(&Bs[r][cc]) = v;
        }
        __syncthreads();
#pragma unroll
        for (int kc = 0; kc < BK; kc += 32) {
            short8 a[2], b[4];
#pragma unroll
            for (int mf = 0; mf < 2; ++mf)
                a[mf] = *reinterpret_cast<const short8*>(&As[w * 32 + mf * 16 + (lane & 15)][kc + (lane >> 4) * 8]);
#pragma unroll
            for (int nf = 0; nf < 4; ++nf)
                b[nf] = *reinterpret_cast<const short8*>(&Bs[nf * 16 + (lane & 15)][kc + (lane >> 4) * 8]);
#pragma unroll
            for (int mf = 0; mf < 2; ++mf)
#pragma unroll
                for (int nf = 0; nf < 4; ++nf)
                    acc[mf][nf] = __builtin_amdgcn_mfma_f32_16x16x32_bf16(a[mf], b[nf], acc[mf][nf], 0, 0, 0);
        }
        __syncthreads();
    }

#pragma unroll
    for (int mf = 0; mf < 2; ++mf) {
        int mbase = m0 + w * 32 + mf * 16 + (lane >> 4) * 4;
#pragma unroll
        for (int r = 0; r < 4; ++r) {
            int m = mbase + r;
            if (m < M) {
#pragma unroll
                for (int nf = 0; nf < 4; ++nf)
                    C[(size_t)m * ldc + nf * 16 + (lane & 15)] = f2bf(acc[mf][nf][r]);
            }
        }
    }

    float asl[4], adl[4];
#pragma unroll
    for (int nf = 0; nf < 4; ++nf) {
        int col = nf * 16 + (lane & 15);
        asl[nf] = asrc[col];
        adl[nf] = adst[col];
    }
#pragma unroll
    for (int mf = 0; mf < 2; ++mf) {
#pragma unroll
        for (int r = 0; r < 4; ++r) {
            float ps = 0.f, pd = 0.f;
#pragma unroll
            for (int nf = 0; nf < 4; ++nf) {
                ps = fmaf(acc[mf][nf][r], asl[nf], ps);
                pd = fmaf(acc[mf][nf][r], adl[nf], pd);
            }
#pragma unroll
            for (int o = 1; o < 16; o <<= 1) {
                ps += __shfl_xor(ps, o, 64);
                pd += __shfl_xor(pd, o, 64);
            }
            int m = m0 + w * 32 + mf * 16 + (lane >> 4) * 4 + r;
            if ((lane & 15) == 0 && m < M) {
                a_s[(size_t)m] = ps;
                a_d[(size_t)m] = pd;
            }
        }
    }
}

// ---------------- fused softmax + gather + BN-stats; y out in bf16 ----------------
template<int H, int C>
__global__ __launch_bounds__(256)
void gat_fused2(const int* __restrict__ offs, const int* __restrict__ ssrc,
                const float* __restrict__ a_s, const float* __restrict__ a_d,
                const ushort* __restrict__ hf, const float* __restrict__ bias,
                ushort* __restrict__ ybuf, float* __restrict__ bnsum)
{
    constexpr int V = (H * C) / 32;   // 8 (H=4) or 2 (H=1)
    constexpr int OF = H * C;         // 256 or 64
    __shared__ float alsh[4][2][64 * H];
    __shared__ int   ssh[4][2][64];
    __shared__ float ysh[8][OF];
    const int tid = threadIdx.x;
    const int lane = tid & 63;
    const int wv = tid >> 6;
    const int half = lane >> 5;
    const int ll = lane & 31;
    const int dl = wv * 2 + half;
    const int dst = blockIdx.x * 8 + dl;
    const int e0 = offs[dst], e1 = offs[dst + 1];
    const int deg = e1 - e0;
    const int hd = (ll * V) / C;

    float ad[H];
    if constexpr (H == 4) {
        float4 v = *reinterpret_cast<const float4*>(a_d + (size_t)dst * 4);
        ad[0] = v.x; ad[1] = v.y; ad[2] = v.z; ad[3] = v.w;
    } else ad[0] = a_d[dst];

    float acc[V];
#pragma unroll
    for (int k = 0; k < V; ++k) acc[k] = 0.f;

    if (deg <= 64) {
        const bool a0 = ll < deg;
        const bool a1 = 32 + ll < deg;
        const int s0 = ssrc[e0 + (a0 ? ll : 0)];
        const int s1 = ssrc[e0 + (a1 ? 32 + ll : 0)];
        float l0[H], l1[H], mx[H], sm[H];
        if constexpr (H == 4) {
            float4 v0 = *reinterpret_cast<const float4*>(a_s + (size_t)s0 * 4);
            float4 v1 = *reinterpret_cast<const float4*>(a_s + (size_t)s1 * 4);
            l0[0] = lrelu(v0.x + ad[0]); l0[1] = lrelu(v0.y + ad[1]);
            l0[2] = lrelu(v0.z + ad[2]); l0[3] = lrelu(v0.w + ad[3]);
            l1[0] = lrelu(v1.x + ad[0]); l1[1] = lrelu(v1.y + ad[1]);
            l1[2] = lrelu(v1.z + ad[2]); l1[3] = lrelu(v1.w + ad[3]);
        } else {
            l0[0] = lrelu(a_s[s0] + ad[0]);
            l1[0] = lrelu(a_s[s1] + ad[0]);
        }
#pragma unroll
        for (int t = 0; t < H; ++t) {
            float m = a0 ? l0[t] : -INFINITY;
            if (a1) m = fmaxf(m, l1[t]);
#pragma unroll
            for (int o = 1; o < 32; o <<= 1) m = fmaxf(m, __shfl_xor(m, o, 64));
            mx[t] = m;
            float s = (a0 ? __expf(l0[t] - m) : 0.f) + (a1 ? __expf(l1[t] - m) : 0.f);
#pragma unroll
            for (int o = 1; o < 32; o <<= 1) s += __shfl_xor(s, o, 64);
            sm[t] = s;
        }
        float inv[H];
#pragma unroll
        for (int t = 0; t < H; ++t) inv[t] = 1.f / (sm[t] + 1e-16f);
        if (a0) {
            ssh[wv][half][ll] = s0;
            if constexpr (H == 4) {
                float4 av = {__expf(l0[0] - mx[0]) * inv[0], __expf(l0[1] - mx[1]) * inv[1],
                             __expf(l0[2] - mx[2]) * inv[2], __expf(l0[3] - mx[3]) * inv[3]};
                *reinterpret_cast<float4*>(&alsh[wv][half][ll * 4]) = av;
            } else alsh[wv][half][ll] = __expf(l0[0] - mx[0]) * inv[0];
        }
        if (a1) {
            ssh[wv][half][32 + ll] = s1;
            if constexpr (H == 4) {
                float4 av = {__expf(l1[0] - mx[0]) * inv[0], __expf(l1[1] - mx[1]) * inv[1],
                             __expf(l1[2] - mx[2]) * inv[2], __expf(l1[3] - mx[3]) * inv[3]};
                *reinterpret_cast<float4*>(&alsh[wv][half][(32 + ll) * 4]) = av;
            } else alsh[wv][half][32 + ll] = __expf(l1[0] - mx[0]) * inv[0];
        }

        const ushort* hlane = hf + (size_t)ll * V;
        int j = 0;
        for (; j + 3 < deg; j += 4) {
            int sj[4]; float al[4];
#pragma unroll
            for (int k = 0; k < 4; ++k) {
                sj[k] = ssh[wv][half][j + k];
                al[k] = alsh[wv][half][(j + k) * H + hd];
            }
            if constexpr (V == 8) {
                short8 hv[4];
#pragma unroll
                for (int k = 0; k < 4; ++k)
                    hv[k] = *reinterpret_cast<const short8*>(hlane + (size_t)sj[k] * OF);
#pragma unroll
                for (int k = 0; k < 4; ++k)
#pragma unroll
                    for (int i = 0; i < 8; ++i)
                        acc[i] = fmaf(al[k], bf2f((ushort)hv[k][i]), acc[i]);
            } else {
                ushort2 hv[4];
#pragma unroll
                for (int k = 0; k < 4; ++k)
                    hv[k] = *reinterpret_cast<const ushort2*>(hlane + (size_t)sj[k] * OF);
#pragma unroll
                for (int k = 0; k < 4; ++k) {
                    acc[0] = fmaf(al[k], bf2f(hv[k].x), acc[0]);
                    acc[1] = fmaf(al[k], bf2f(hv[k].y), acc[1]);
                }
            }
        }
        for (; j < deg; ++j) {
            int sj = ssh[wv][half][j];
            float al = alsh[wv][half][j * H + hd];
            if constexpr (V == 8) {
                short8 hv = *reinterpret_cast<const short8*>(hlane + (size_t)sj * OF);
#pragma unroll
                for (int i = 0; i < 8; ++i)
                    acc[i] = fmaf(al, bf2f((ushort)hv[i]), acc[i]);
            } else {
                ushort2 hv = *reinterpret_cast<const ushort2*>(hlane + (size_t)sj * OF);
                acc[0] = fmaf(al, bf2f(hv.x), acc[0]);
                acc[1] = fmaf(al, bf2f(hv.y), acc[1]);
            }
        }
    } else {
        float mx[H], sm[H];
#pragma unroll
        for (int t = 0; t < H; ++t) mx[t] = -INFINITY;
        for (int e = e0 + ll; e < e1; e += 32) {
            int s = ssrc[e];
            float asv[H];
            if constexpr (H == 4) {
                float4 v = *reinterpret_cast<const float4*>(a_s + (size_t)s * 4);
                asv[0] = v.x; asv[1] = v.y; asv[2] = v.z; asv[3] = v.w;
            } else asv[0] = a_s[s];
#pragma unroll
            for (int t = 0; t < H; ++t) mx[t] = fmaxf(mx[t], lrelu(asv[t] + ad[t]));
        }
#pragma unroll
        for (int t = 0; t < H; ++t)
#pragma unroll
            for (int o = 1; o < 32; o <<= 1) mx[t] = fmaxf(mx[t], __shfl_xor(mx[t], o, 64));
#pragma unroll
        for (int t = 0; t < H; ++t) sm[t] = 0.f;
        for (int e = e0 + ll; e < e1; e += 32) {
            int s = ssrc[e];
            float asv[H];
            if constexpr (H == 4) {
                float4 v = *reinterpret_cast<const float4*>(a_s + (size_t)s * 4);
                asv[0] = v.x; asv[1] = v.y; asv[2] = v.z; asv[3] = v.w;
            } else asv[0] = a_s[s];
#pragma unroll
            for (int t = 0; t < H; ++t) sm[t] += __expf(lrelu(asv[t] + ad[t]) - mx[t]);
        }
#pragma unroll
        for (int t = 0; t < H; ++t)
#pragma unroll
            for (int o = 1; o < 32; o <<= 1) sm[t] += __shfl_xor(sm[t], o, 64);

        float mxl = mx[0], sml = sm[0], adl = ad[0];
#pragma unroll
        for (int t = 1; t < H; ++t) {
            mxl = (hd == t) ? mx[t] : mxl;
            sml = (hd == t) ? sm[t] : sml;
            adl = (hd == t) ? ad[t] : adl;
        }
        const float invl = 1.f / (sml + 1e-16f);
        const ushort* hlane = hf + (size_t)ll * V;
        for (int e = e0; e < e1; ++e) {
            int s0 = ssrc[e];
            float al0 = __expf(lrelu(a_s[(size_t)s0 * H + hd] + adl) - mxl) * invl;
            if constexpr (V == 8) {
                short8 hv = *reinterpret_cast<const short8*>(hlane + (size_t)s0 * OF);
#pragma unroll
                for (int i = 0; i < 8; ++i)
                    acc[i] = fmaf(al0, bf2f((ushort)hv[i]), acc[i]);
            } else {
                ushort2 hv = *reinterpret_cast<const ushort2*>(hlane + (size_t)s0 * OF);
                acc[0] = fmaf(al0, bf2f(hv.x), acc[0]);
                acc[1] = fmaf(al0, bf2f(hv.y), acc[1]);
            }
        }
    }

    // epilogue: + bias, ELU -> y (bf16 out + LDS stage for BN stats)
    float res[V];
#pragma unroll
    for (int i = 0; i < V; ++i) {
        float t = acc[i] + bias[ll * V + i];
        res[i] = t > 0.f ? t : (expf(t) - 1.f);
    }
    if constexpr (V == 8) {
        short8 yv = {(short)f2bf(res[0]), (short)f2bf(res[1]), (short)f2bf(res[2]), (short)f2bf(res[3]),
                     (short)f2bf(res[4]), (short)f2bf(res[5]), (short)f2bf(res[6]), (short)f2bf(res[7])};
        *reinterpret_cast<short8*>(&ybuf[(size_t)dst * OF + ll * 8]) = yv;
        *reinterpret_cast<f32x4*>(&ysh[dl][ll * 8 + 0]) = f32x4{res[0], res[1], res[2], res[3]};
        *reinterpret_cast<f32x4*>(&ysh[dl][ll * 8 + 4]) = f32x4{res[4], res[5], res[6], res[7]};
    } else {
        ushort2 yv = {f2bf(res[0]), f2bf(res[1])};
        *reinterpret_cast<ushort2*>(&ybuf[(size_t)dst * OF + ll * 2]) = yv;
        ysh[dl][ll * 2 + 0] = res[0];
        ysh[dl][ll * 2 + 1] = res[1];
    }
    __syncthreads();
    if (tid < OF) {
        float s = 0.f, s2 = 0.f;
#pragma unroll
        for (int d = 0; d < 8; ++d) {
            float v = ysh[d][tid];
            s += v;
            s2 = fmaf(v, v, s2);
        }
        int slot = blockIdx.x & 7;
        atomicAdd(&bnsum[(size_t)slot * 2 * OF + tid], s);
        atomicAdd(&bnsum[(size_t)slot * 2 * OF + OF + tid], s2);
    }
}

// ---------------- edge bucketing ----------------
__global__ void edge_count(const int* __restrict__ ei, int* __restrict__ counts)
{
    int i = blockIdx.x * blockDim.x + threadIdx.x;
    if (i >= E_TOT) return;
    int dst = (i < NUM_E) ? ei[NUM_E + i] : (i - NUM_E);
    atomicAdd(&counts[dst], 1);
}

__global__ void edge_scatter(const int* __restrict__ ei, int* __restrict__ cursor,
                             int* __restrict__ ssrc)
{
    int i = blockIdx.x * blockDim.x + threadIdx.x;
    if (i >= E_TOT) return;
    int src, dst;
    if (i < NUM_E) { src = ei[i]; dst = ei[NUM_E + i]; }
    else           { src = dst = i - NUM_E; }
    int pos = atomicAdd(&cursor[dst], 1);
    ssrc[pos] = src;
}

// ---------------- scan ----------------
__global__ void scan_block(const int* __restrict__ in, int n,
                           int* __restrict__ incl, int* __restrict__ bsum)
{
    __shared__ int sh[256];
    int tid = threadIdx.x;
    int i = blockIdx.x * 256 + tid;
    int v = (i < n) ? in[i] : 0;
    sh[tid] = v;
    __syncthreads();
    for (int o = 1; o < 256; o <<= 1) {
        int t = (tid >= o) ? sh[tid - o] : 0;
        __syncthreads();
        sh[tid] += t;
        __syncthreads();
    }
    if (i < n) incl[i] = sh[tid];
    if (tid == 255) bsum[blockIdx.x] = sh[255];
}

__global__ void scan_final(const int* __restrict__ incl, const int* __restrict__ in,
                           const int* __restrict__ bsum, int n,
                           int* __restrict__ offs, int* __restrict__ cursor)
{
    __shared__ int sh[256];
    const int tid = threadIdx.x;
    const int bi = blockIdx.x;
    sh[tid] = (tid < bi) ? bsum[tid] : 0;
    __syncthreads();
    for (int o = 128; o > 0; o >>= 1) {
        if (tid < o) sh[tid] += sh[tid + o];
        __syncthreads();
    }
    const int pref = sh[0];
    int i = bi * 256 + tid;
    if (i >= n) return;
    int excl = incl[i] - in[i] + pref;
    offs[i] = excl;
    cursor[i] = excl;
    if (i == n - 1) offs[n] = incl[i] + pref;
}

// ---------------- BN finalize: reduce 8 slots -> scale/shift; self-zero bnsum ----------------
template<int OF>
__global__ void bn_finalize(float* __restrict__ bnsum, const float* __restrict__ gamma,
                            const float* __restrict__ beta, float* __restrict__ ss)
{
    int c = threadIdx.x;
    if (c >= OF) return;
    float s = 0.f, s2 = 0.f;
#pragma unroll
    for (int slot = 0; slot < 8; ++slot) {
        s += bnsum[(size_t)slot * 2 * OF + c];
        s2 += bnsum[(size_t)slot * 2 * OF + OF + c];
        bnsum[(size_t)slot * 2 * OF + c] = 0.f;
        bnsum[(size_t)slot * 2 * OF + OF + c] = 0.f;
    }
    float mean = s / (float)N_NODES;
    float var = s2 / (float)N_NODES - mean * mean;
    float inv = rsqrtf(var + EPS_BN);
    float sc = inv * gamma[c];
    ss[c] = sc;
    ss[OF + c] = beta[c] - mean * sc;
}

// ---------------- BN apply (pure streaming, no atomics): y bf16 -> xs fp32 ----------------
template<int OF>
__global__ __launch_bounds__(256)
void bn_apply(const ushort* __restrict__ y, float* __restrict__ xs, int ldx,
              const float* __restrict__ ss)
{
    constexpr int TPR = OF / 8;          // threads per row: 32 or 8
    constexpr int RPB = 256 / TPR;       // rows per block: 8 or 32
    const int tid = threadIdx.x;
    const int r = blockIdx.x * RPB + tid / TPR;
    const int c = (tid % TPR) * 8;
    if (r >= N_NODES) return;
    short8 yv = *reinterpret_cast<const short8*>(y + (size_t)r * OF + c);
    float4 s0 = *reinterpret_cast<const float4*>(&ss[c]);
    float4 s1 = *reinterpret_cast<const float4*>(&ss[c + 4]);
    float4 h0 = *reinterpret_cast<const float4*>(&ss[OF + c]);
    float4 h1 = *reinterpret_cast<const float4*>(&ss[OF + c + 4]);
    float4 v0, v1;
    v0.x = fmaf(bf2f((ushort)yv[0]), s0.x, h0.x);
    v0.y = fmaf(bf2f((ushort)yv[1]), s0.y, h0.y);
    v0.z = fmaf(bf2f((ushort)yv[2]), s0.z, h0.z);
    v0.w = fmaf(bf2f((ushort)yv[3]), s0.w, h0.w);
    v1.x = fmaf(bf2f((ushort)yv[4]), s1.x, h1.x);
    v1.y = fmaf(bf2f((ushort)yv[5]), s1.y, h1.y);
    v1.z = fmaf(bf2f((ushort)yv[6]), s1.z, h1.z);
    v1.w = fmaf(bf2f((ushort)yv[7]), s1.w, h1.w);
    *reinterpret_cast<float4*>(&xs[(size_t)r * ldx + c]) = v0;
    *reinterpret_cast<float4*>(&xs[(size_t)r * ldx + c + 4]) = v1;
}

// ---------------- pooling from y bf16: sum(y*sc+sh) = sc*S + n*sh ----------------
// one block per (graph, quarter); OF threads; 4 atomics per output address total.
template<int OF>
__global__ void pool_g(const ushort* __restrict__ y, const int* __restrict__ goffs,
                       const float* __restrict__ ss, float* __restrict__ pool, int poff)
{
    const int g = blockIdx.x >> 2, part = blockIdx.x & 3;
    const int c = threadIdx.x;
    const int r0 = goffs[g], r1 = goffs[g + 1];
    const int cnt = r1 - r0;
    const int p0 = r0 + (cnt * part) / 4;
    const int p1 = r0 + (cnt * (part + 1)) / 4;
    if (p1 <= p0) return;
    float s = 0.f;
    for (int r = p0; r < p1; ++r) s += bf2f(y[(size_t)r * OF + c]);
    float v = fmaf(ss[c], s, (float)(p1 - p0) * ss[OF + c]);
    atomicAdd(&pool[(size_t)g * XS_COLS + poff + c], v);
}

extern "C" void kernel_launch(void* const* d_in, const int* in_sizes, int n_in,
                              void* d_out, int out_size, void* d_ws, size_t ws_size,
                              hipStream_t stream)
{
    const float* x     = (const float*)d_in[0];
    const int*   ei    = (const int*)d_in[1];
    const int*   batch = (const int*)d_in[2];
    const float* W[3]    = {(const float*)d_in[3],  (const float*)d_in[9],  (const float*)d_in[15]};
    const float* asrc[3] = {(const float*)d_in[4],  (const float*)d_in[10], (const float*)d_in[16]};
    const float* adst[3] = {(const float*)d_in[5],  (const float*)d_in[11], (const float*)d_in[17]};
    const float* bia[3]  = {(const float*)d_in[6],  (const float*)d_in[12], (const float*)d_in[18]};
    const float* gam[3]  = {(const float*)d_in[7],  (const float*)d_in[13], (const float*)d_in[19]};
    const float* bet[3]  = {(const float*)d_in[8],  (const float*)d_in[14], (const float*)d_in[20]};

    char* wp = (char*)d_ws;
    auto alloc = [&](size_t bytes) -> void* {
        void* p = (void*)wp;
        wp += (bytes + 255) & ~(size_t)255;
        return p;
    };
    ushort* hbf   = (ushort*)alloc((size_t)N_NODES * 256 * 2);
    ushort* ybuf  = (ushort*)alloc((size_t)M_PAD * 256 * 2);
    float*  a_s   = (float*)alloc((size_t)N_NODES * 4 * 4);
    float*  a_d   = (float*)alloc((size_t)N_NODES * 4 * 4);
    int*    counts = (int*)alloc((size_t)N_NODES * 4);
    int*    offs   = (int*)alloc((size_t)(N_NODES + 1) * 4);
    int*    cursor = (int*)alloc((size_t)N_NODES * 4);
    int*    incl   = (int*)alloc((size_t)N_NODES * 4);
    int*    bsums  = (int*)alloc(1024);
    int*    ssrc   = (int*)alloc((size_t)E_TOT * 4);
    float*  bnsum  = (float*)alloc((size_t)8 * 2 * 256 * 4);
    float*  bnss   = (float*)alloc(2 * 256 * 4);
    int*    goffs  = (int*)alloc((NGRAPH + 1) * 4);
    ushort* Wt0    = (ushort*)alloc(256 * 128 * 2);
    ushort* Wt1    = (ushort*)alloc(256 * 256 * 2);
    ushort* Wt2    = (ushort*)alloc(64 * 256 * 2);

    float* pool = (float*)d_out;                    // [128, 576]
    float* xs   = pool + (size_t)NGRAPH * XS_COLS;  // [50000, 576]

    // ---- setup ----
    hipMemsetAsync(counts, 0, (size_t)N_NODES * 4, stream);
    hipMemsetAsync(pool, 0, (size_t)NGRAPH * XS_COLS * 4, stream);
    hipMemsetAsync(bnsum, 0, (size_t)8 * 2 * 256 * 4, stream);
    edge_count<<<ceil_div(E_TOT, 256), 256, 0, stream>>>(ei, counts);
    const int NSB = ceil_div(N_NODES, 256);
    scan_block<<<NSB, 256, 0, stream>>>(counts, N_NODES, incl, bsums);
    scan_final<<<NSB, 256, 0, stream>>>(incl, counts, bsums, N_NODES, offs, cursor);
    edge_scatter<<<ceil_div(E_TOT, 256), 256, 0, stream>>>(ei, cursor, ssrc);
    graph_bounds<<<ceil_div(N_NODES, 256), 256, 0, stream>>>(batch, goffs);
    const int PREP_ITEMS = 256 * 128 + 256 * 256 + 64 * 256;
    prep_w<<<ceil_div(PREP_ITEMS, 256), 256, 0, stream>>>(W[0], W[1], W[2], Wt0, Wt1, Wt2);

    const int NW2 = ceil_div(N_NODES, 8);   // 6250 (exact)
    const int NMB = ceil_div(N_NODES, 128);

    // ---------------- layer 0: 128 -> 4x64 concat (256) ----------------
    {
        gemm_bf16_w<0><<<NMB, 512, 0, stream>>>(x, 128, nullptr, nullptr, Wt0, 128, hbf, N_NODES, 128,
                                                asrc[0], adst[0], a_s, a_d);
        gat_fused2<4, 64><<<NW2, 256, 0, stream>>>(offs, ssrc, a_s, a_d, hbf, bia[0], ybuf, bnsum);
        bn_finalize<256><<<1, 256, 0, stream>>>(bnsum, gam[0], bet[0], bnss);
        bn_apply<256><<<ceil_div(N_NODES, 8), 256, 0, stream>>>(ybuf, xs + 0, XS_COLS, bnss);
        pool_g<256><<<NGRAPH * 4, 256, 0, stream>>>(ybuf, goffs, bnss, pool, 0);
    }
    // ---------------- layer 1: 256 -> 4x64 concat (256); BN applied in GEMM staging ----------------
    {
        gemm_bf16_w<2><<<NMB, 512, 0, stream>>>(ybuf, 256, bnss, bnss + 256, Wt1, 256, hbf, N_NODES, 256,
                                                asrc[1], adst[1], a_s, a_d);
        gat_fused2<4, 64><<<NW2, 256, 0, stream>>>(offs, ssrc, a_s, a_d, hbf, bia[1], ybuf, bnsum);
        bn_finalize<256><<<1, 256, 0, stream>>>(bnsum, gam[1], bet[1], bnss);
        bn_apply<256><<<ceil_div(N_NODES, 8), 256, 0, stream>>>(ybuf, xs + 256, XS_COLS, bnss);
        pool_g<256><<<NGRAPH * 4, 256, 0, stream>>>(ybuf, goffs, bnss, pool, 256);
    }
    // ---------------- layer 2: 256 -> 1x64; BN applied in GEMM staging ----------------
    {
        gemm_bf16_n<<<NMB, 256, 0, stream>>>(ybuf, 256, bnss, bnss + 256, Wt2, 256, hbf, 64, N_NODES, 256,
                                             asrc[2], adst[2], a_s, a_d);
        gat_fused2<1, 64><<<NW2, 256, 0, stream>>>(offs, ssrc, a_s, a_d, hbf, bia[2], ybuf, bnsum);
        bn_finalize<64><<<1, 64, 0, stream>>>(bnsum, gam[2], bet[2], bnss);
        bn_apply<64><<<ceil_div(N_NODES, 32), 256, 0, stream>>>(ybuf, xs + 512, XS_COLS, bnss);
        pool_g<64><<<NGRAPH * 4, 64, 0, stream>>>(ybuf, goffs, bnss, pool, 512);
    }
}

// Round 11
// 463.694 us; speedup vs baseline: 1.5078x; 1.0188x over previous
//
#include <hip/hip_runtime.h>
#include <math.h>

#define N_NODES 50000
#define NUM_E   800000
#define E_TOT   (NUM_E + N_NODES)   // 850000 (self loops appended)
#define M_PAD   50048               // N_NODES rounded up to 128
#define NGRAPH  128
#define XS_COLS 576
#define EPS_BN  1e-5f

static inline int ceil_div(int a, int b) { return (a + b - 1) / b; }

typedef __attribute__((ext_vector_type(8))) short short8;
typedef __attribute__((ext_vector_type(4))) float f32x4;

__device__ __forceinline__ float bf2f(ushort u) {
    union { unsigned int i; float f; } v; v.i = ((unsigned int)u) << 16; return v.f;
}
__device__ __forceinline__ ushort f2bf(float f) {
    union { float f; unsigned int i; } v; v.f = f;
    unsigned int r = v.i + 0x7FFF + ((v.i >> 16) & 1);
    return (ushort)(r >> 16);
}
__device__ __forceinline__ float lrelu(float l) { return l > 0.f ? l : 0.2f * l; }

// ---------------- prep: 3 weight transposes ----------------
__global__ __launch_bounds__(256)
void prep_w(const float* __restrict__ W0, const float* __restrict__ W1,
            const float* __restrict__ W2,
            ushort* __restrict__ Wt0, ushort* __restrict__ Wt1, ushort* __restrict__ Wt2)
{
    int j = blockIdx.x * 256 + threadIdx.x;
    if (j < 256 * 128) { Wt0[j] = f2bf(W0[(size_t)(j % 128) * 256 + (j / 128)]); return; }
    j -= 256 * 128;
    if (j < 256 * 256) { Wt1[j] = f2bf(W1[(size_t)(j % 256) * 256 + (j / 256)]); return; }
    j -= 256 * 256;
    if (j < 64 * 256)  { Wt2[j] = f2bf(W2[(size_t)(j % 256) * 64 + (j / 256)]); }
}

// ---------------- wide bf16 MFMA GEMM (BM=128, BN=256, 8 waves) ----------------
// AMODE 0: A fp32 (convert in staging).  AMODE 2: A bf16 ybuf + BN scale/shift in staging.
template<int AMODE>
__global__ __launch_bounds__(512)
void gemm_bf16_w(const void* __restrict__ Av, int lda,
                 const float* __restrict__ bnsc, const float* __restrict__ bnsh,
                 const ushort* __restrict__ Bt, int ldb,
                 ushort* __restrict__ C, int M, int K,
                 const float* __restrict__ asrc, const float* __restrict__ adst,
                 float* __restrict__ a_s, float* __restrict__ a_d)
{
    __shared__ __align__(16) ushort As[128][64 + 8];
    __shared__ __align__(16) ushort Bs[256][64 + 8];
    const int tid = threadIdx.x;
    const int lane = tid & 63;
    const int w = tid >> 6;
    const int m0 = blockIdx.x * 128;

    f32x4 acc[16] = {};

    for (int k0 = 0; k0 < K; k0 += 64) {
#pragma unroll
        for (int j = 0; j < 2; ++j) {
            int c = tid + j * 512;
            int r = c >> 3, cc = (c & 7) * 8;
            if constexpr (AMODE == 0) {
                const float* Af = (const float*)Av;
                int m = m0 + r; if (m >= M) m = M - 1;
                float4 v0 = *reinterpret_cast<const float4*>(Af + (size_t)m * lda + k0 + cc);
                float4 v1 = *reinterpret_cast<const float4*>(Af + (size_t)m * lda + k0 + cc + 4);
                short8 v = {(short)f2bf(v0.x), (short)f2bf(v0.y), (short)f2bf(v0.z), (short)f2bf(v0.w),
                            (short)f2bf(v1.x), (short)f2bf(v1.y), (short)f2bf(v1.z), (short)f2bf(v1.w)};
                *reinterpret_cast<short8*>(&As[r][cc]) = v;
            } else {
                const ushort* Ab = (const ushort*)Av;   // M_PAD rows allocated
                short8 y = *reinterpret_cast<const short8*>(Ab + (size_t)(m0 + r) * lda + k0 + cc);
                float4 sa = *reinterpret_cast<const float4*>(&bnsc[k0 + cc]);
                float4 sb = *reinterpret_cast<const float4*>(&bnsc[k0 + cc + 4]);
                float4 ha = *reinterpret_cast<const float4*>(&bnsh[k0 + cc]);
                float4 hb = *reinterpret_cast<const float4*>(&bnsh[k0 + cc + 4]);
                short8 v;
                v[0] = (short)f2bf(fmaf(bf2f((ushort)y[0]), sa.x, ha.x));
                v[1] = (short)f2bf(fmaf(bf2f((ushort)y[1]), sa.y, ha.y));
                v[2] = (short)f2bf(fmaf(bf2f((ushort)y[2]), sa.z, ha.z));
                v[3] = (short)f2bf(fmaf(bf2f((ushort)y[3]), sa.w, ha.w));
                v[4] = (short)f2bf(fmaf(bf2f((ushort)y[4]), sb.x, hb.x));
                v[5] = (short)f2bf(fmaf(bf2f((ushort)y[5]), sb.y, hb.y));
                v[6] = (short)f2bf(fmaf(bf2f((ushort)y[6]), sb.z, hb.z));
                v[7] = (short)f2bf(fmaf(bf2f((ushort)y[7]), sb.w, hb.w));
                *reinterpret_cast<short8*>(&As[r][cc]) = v;
            }
        }
#pragma unroll
        for (int j = 0; j < 4; ++j) {
            int c = tid + j * 512;
            int r = c >> 3, cc = (c & 7) * 8;
            short8 v = *reinterpret_cast<const short8*>(Bt + (size_t)r * ldb + k0 + cc);
            *reinterpret_cast<short8*>(&Bs[r][cc]) = v;
        }
        __syncthreads();
#pragma unroll
        for (int kc = 0; kc < 64; kc += 32) {
            short8 a = *reinterpret_cast<const short8*>(&As[w * 16 + (lane & 15)][kc + (lane >> 4) * 8]);
#pragma unroll
            for (int nf = 0; nf < 16; ++nf) {
                short8 b = *reinterpret_cast<const short8*>(&Bs[nf * 16 + (lane & 15)][kc + (lane >> 4) * 8]);
                acc[nf] = __builtin_amdgcn_mfma_f32_16x16x32_bf16(a, b, acc[nf], 0, 0, 0);
            }
        }
        __syncthreads();
    }

    const int mbase = m0 + w * 16 + (lane >> 4) * 4;
#pragma unroll
    for (int r = 0; r < 4; ++r) {
        int m = mbase + r;
        if (m < M) {
#pragma unroll
            for (int nf = 0; nf < 16; ++nf)
                C[(size_t)m * 256 + nf * 16 + (lane & 15)] = f2bf(acc[nf][r]);
        }
    }

    float asl[16], adl[16];
#pragma unroll
    for (int nf = 0; nf < 16; ++nf) {
        int col = nf * 16 + (lane & 15);
        asl[nf] = asrc[col];
        adl[nf] = adst[col];
    }
#pragma unroll
    for (int r = 0; r < 4; ++r) {
        float ps[4] = {0.f, 0.f, 0.f, 0.f};
        float pd[4] = {0.f, 0.f, 0.f, 0.f};
#pragma unroll
        for (int nf = 0; nf < 16; ++nf) {
            int h = nf >> 2;
            ps[h] = fmaf(acc[nf][r], asl[nf], ps[h]);
            pd[h] = fmaf(acc[nf][r], adl[nf], pd[h]);
        }
#pragma unroll
        for (int h = 0; h < 4; ++h) {
#pragma unroll
            for (int o = 1; o < 16; o <<= 1) {
                ps[h] += __shfl_xor(ps[h], o, 64);
                pd[h] += __shfl_xor(pd[h], o, 64);
            }
        }
        int m = mbase + r;
        if ((lane & 15) == 0 && m < M) {
#pragma unroll
            for (int h = 0; h < 4; ++h) {
                a_s[(size_t)m * 4 + h] = ps[h];
                a_d[(size_t)m * 4 + h] = pd[h];
            }
        }
    }
}

// ---------------- narrow GEMM for layer 2 (BN=64, H=1 epilogue, BN-staged A) ----------------
__global__ __launch_bounds__(256)
void gemm_bf16_n(const ushort* __restrict__ A, int lda,
                 const float* __restrict__ bnsc, const float* __restrict__ bnsh,
                 const ushort* __restrict__ Bt, int ldb,
                 ushort* __restrict__ C, int ldc, int M, int K,
                 const float* __restrict__ asrc, const float* __restrict__ adst,
                 float* __restrict__ a_s, float* __restrict__ a_d)
{
    constexpr int BM = 128, BN = 64, BK = 64;
    __shared__ __align__(16) ushort As[BM][BK + 8];
    __shared__ __align__(16) ushort Bs[BN][BK + 8];
    const int tid = threadIdx.x;
    const int lane = tid & 63;
    const int w = tid >> 6;
    const int m0 = blockIdx.x * BM;

    f32x4 acc[2][4] = {};

    for (int k0 = 0; k0 < K; k0 += BK) {
#pragma unroll
        for (int j = 0; j < 4; ++j) {
            int c = tid + j * 256;
            int r = c >> 3, cc = (c & 7) * 8;
            short8 y = *reinterpret_cast<const short8*>(A + (size_t)(m0 + r) * lda + k0 + cc);
            float4 sa = *reinterpret_cast<const float4*>(&bnsc[k0 + cc]);
            float4 sb = *reinterpret_cast<const float4*>(&bnsc[k0 + cc + 4]);
            float4 ha = *reinterpret_cast<const float4*>(&bnsh[k0 + cc]);
            float4 hb = *reinterpret_cast<const float4*>(&bnsh[k0 + cc + 4]);
            short8 v;
            v[0] = (short)f2bf(fmaf(bf2f((ushort)y[0]), sa.x, ha.x));
            v[1] = (short)f2bf(fmaf(bf2f((ushort)y[1]), sa.y, ha.y));
            v[2] = (short)f2bf(fmaf(bf2f((ushort)y[2]), sa.z, ha.z));
            v[3] = (short)f2bf(fmaf(bf2f((ushort)y[3]), sa.w, ha.w));
            v[4] = (short)f2bf(fmaf(bf2f((ushort)y[4]), sb.x, hb.x));
            v[5] = (short)f2bf(fmaf(bf2f((ushort)y[5]), sb.y, hb.y));
            v[6] = (short)f2bf(fmaf(bf2f((ushort)y[6]), sb.z, hb.z));
            v[7] = (short)f2bf(fmaf(bf2f((ushort)y[7]), sb.w, hb.w));
            *reinterpret_cast<short8*>(&As[r][cc]) = v;
        }
#pragma unroll
        for (int j = 0; j < 2; ++j) {
            int c = tid + j * 256;
            int r = c >> 3, cc = (c & 7) * 8;
            short8 v = *reinterpret_cast<const short8*>(Bt + (size_t)r * ldb + k0 + cc);
            *reinterpret_cast<short8*>(&Bs[r][cc]) = v;
        }
        __syncthreads();
#pragma unroll
        for (int kc = 0; kc < BK; kc += 32) {
            short8 a[2], b[4];
#pragma unroll
            for (int mf = 0; mf < 2; ++mf)
                a[mf] = *reinterpret_cast<const short8*>(&As[w * 32 + mf * 16 + (lane & 15)][kc + (lane >> 4) * 8]);
#pragma unroll
            for (int nf = 0; nf < 4; ++nf)
                b[nf] = *reinterpret_cast<const short8*>(&Bs[nf * 16 + (lane & 15)][kc + (lane >> 4) * 8]);
#pragma unroll
            for (int mf = 0; mf < 2; ++mf)
#pragma unroll
                for (int nf = 0; nf < 4; ++nf)
                    acc[mf][nf] = __builtin_amdgcn_mfma_f32_16x16x32_bf16(a[mf], b[nf], acc[mf][nf], 0, 0, 0);
        }
        __syncthreads();
    }

#pragma unroll
    for (int mf = 0; mf < 2; ++mf) {
        int mbase = m0 + w * 32 + mf * 16 + (lane >> 4) * 4;
#pragma unroll
        for (int r = 0; r < 4; ++r) {
            int m = mbase + r;
            if (m < M) {
#pragma unroll
                for (int nf = 0; nf < 4; ++nf)
                    C[(size_t)m * ldc + nf * 16 + (lane & 15)] = f2bf(acc[mf][nf][r]);
            }
        }
    }

    float asl[4], adl[4];
#pragma unroll
    for (int nf = 0; nf < 4; ++nf) {
        int col = nf * 16 + (lane & 15);
        asl[nf] = asrc[col];
        adl[nf] = adst[col];
    }
#pragma unroll
    for (int mf = 0; mf < 2; ++mf) {
#pragma unroll
        for (int r = 0; r < 4; ++r) {
            float ps = 0.f, pd = 0.f;
#pragma unroll
            for (int nf = 0; nf < 4; ++nf) {
                ps = fmaf(acc[mf][nf][r], asl[nf], ps);
                pd = fmaf(acc[mf][nf][r], adl[nf], pd);
            }
#pragma unroll
            for (int o = 1; o < 16; o <<= 1) {
                ps += __shfl_xor(ps, o, 64);
                pd += __shfl_xor(pd, o, 64);
            }
            int m = m0 + w * 32 + mf * 16 + (lane >> 4) * 4 + r;
            if ((lane & 15) == 0 && m < M) {
                a_s[(size_t)m] = ps;
                a_d[(size_t)m] = pd;
            }
        }
    }
}

// ---------------- fused softmax + gather + BN-stats; y out in bf16 ----------------
template<int H, int C>
__global__ __launch_bounds__(256)
void gat_fused2(const int* __restrict__ offs, const int* __restrict__ ssrc,
                const float* __restrict__ a_s, const float* __restrict__ a_d,
                const ushort* __restrict__ hf, const float* __restrict__ bias,
                ushort* __restrict__ ybuf, float* __restrict__ bnsum)
{
    constexpr int V = (H * C) / 32;   // 8 (H=4) or 2 (H=1)
    constexpr int OF = H * C;         // 256 or 64
    __shared__ float alsh[4][2][64 * H];
    __shared__ int   ssh[4][2][64];
    __shared__ float ysh[8][OF];
    const int tid = threadIdx.x;
    const int lane = tid & 63;
    const int wv = tid >> 6;
    const int half = lane >> 5;
    const int ll = lane & 31;
    const int dl = wv * 2 + half;
    const int dst = blockIdx.x * 8 + dl;
    const int e0 = offs[dst], e1 = offs[dst + 1];
    const int deg = e1 - e0;
    const int hd = (ll * V) / C;

    float ad[H];
    if constexpr (H == 4) {
        float4 v = *reinterpret_cast<const float4*>(a_d + (size_t)dst * 4);
        ad[0] = v.x; ad[1] = v.y; ad[2] = v.z; ad[3] = v.w;
    } else ad[0] = a_d[dst];

    float acc[V];
#pragma unroll
    for (int k = 0; k < V; ++k) acc[k] = 0.f;

    if (deg <= 64) {
        const bool a0 = ll < deg;
        const bool a1 = 32 + ll < deg;
        const int s0 = ssrc[e0 + (a0 ? ll : 0)];
        const int s1 = ssrc[e0 + (a1 ? 32 + ll : 0)];
        float l0[H], l1[H], mx[H], sm[H];
        if constexpr (H == 4) {
            float4 v0 = *reinterpret_cast<const float4*>(a_s + (size_t)s0 * 4);
            float4 v1 = *reinterpret_cast<const float4*>(a_s + (size_t)s1 * 4);
            l0[0] = lrelu(v0.x + ad[0]); l0[1] = lrelu(v0.y + ad[1]);
            l0[2] = lrelu(v0.z + ad[2]); l0[3] = lrelu(v0.w + ad[3]);
            l1[0] = lrelu(v1.x + ad[0]); l1[1] = lrelu(v1.y + ad[1]);
            l1[2] = lrelu(v1.z + ad[2]); l1[3] = lrelu(v1.w + ad[3]);
        } else {
            l0[0] = lrelu(a_s[s0] + ad[0]);
            l1[0] = lrelu(a_s[s1] + ad[0]);
        }
#pragma unroll
        for (int t = 0; t < H; ++t) {
            float m = a0 ? l0[t] : -INFINITY;
            if (a1) m = fmaxf(m, l1[t]);
#pragma unroll
            for (int o = 1; o < 32; o <<= 1) m = fmaxf(m, __shfl_xor(m, o, 64));
            mx[t] = m;
            float s = (a0 ? __expf(l0[t] - m) : 0.f) + (a1 ? __expf(l1[t] - m) : 0.f);
#pragma unroll
            for (int o = 1; o < 32; o <<= 1) s += __shfl_xor(s, o, 64);
            sm[t] = s;
        }
        float inv[H];
#pragma unroll
        for (int t = 0; t < H; ++t) inv[t] = 1.f / (sm[t] + 1e-16f);
        if (a0) {
            ssh[wv][half][ll] = s0;
            if constexpr (H == 4) {
                float4 av = {__expf(l0[0] - mx[0]) * inv[0], __expf(l0[1] - mx[1]) * inv[1],
                             __expf(l0[2] - mx[2]) * inv[2], __expf(l0[3] - mx[3]) * inv[3]};
                *reinterpret_cast<float4*>(&alsh[wv][half][ll * 4]) = av;
            } else alsh[wv][half][ll] = __expf(l0[0] - mx[0]) * inv[0];
        }
        if (a1) {
            ssh[wv][half][32 + ll] = s1;
            if constexpr (H == 4) {
                float4 av = {__expf(l1[0] - mx[0]) * inv[0], __expf(l1[1] - mx[1]) * inv[1],
                             __expf(l1[2] - mx[2]) * inv[2], __expf(l1[3] - mx[3]) * inv[3]};
                *reinterpret_cast<float4*>(&alsh[wv][half][(32 + ll) * 4]) = av;
            } else alsh[wv][half][32 + ll] = __expf(l1[0] - mx[0]) * inv[0];
        }

        const ushort* hlane = hf + (size_t)ll * V;
        int j = 0;
        for (; j + 3 < deg; j += 4) {
            int sj[4]; float al[4];
#pragma unroll
            for (int k = 0; k < 4; ++k) {
                sj[k] = ssh[wv][half][j + k];
                al[k] = alsh[wv][half][(j + k) * H + hd];
            }
            if constexpr (V == 8) {
                short8 hv[4];
#pragma unroll
                for (int k = 0; k < 4; ++k)
                    hv[k] = *reinterpret_cast<const short8*>(hlane + (size_t)sj[k] * OF);
#pragma unroll
                for (int k = 0; k < 4; ++k)
#pragma unroll
                    for (int i = 0; i < 8; ++i)
                        acc[i] = fmaf(al[k], bf2f((ushort)hv[k][i]), acc[i]);
            } else {
                ushort2 hv[4];
#pragma unroll
                for (int k = 0; k < 4; ++k)
                    hv[k] = *reinterpret_cast<const ushort2*>(hlane + (size_t)sj[k] * OF);
#pragma unroll
                for (int k = 0; k < 4; ++k) {
                    acc[0] = fmaf(al[k], bf2f(hv[k].x), acc[0]);
                    acc[1] = fmaf(al[k], bf2f(hv[k].y), acc[1]);
                }
            }
        }
        for (; j < deg; ++j) {
            int sj = ssh[wv][half][j];
            float al = alsh[wv][half][j * H + hd];
            if constexpr (V == 8) {
                short8 hv = *reinterpret_cast<const short8*>(hlane + (size_t)sj * OF);
#pragma unroll
                for (int i = 0; i < 8; ++i)
                    acc[i] = fmaf(al, bf2f((ushort)hv[i]), acc[i]);
            } else {
                ushort2 hv = *reinterpret_cast<const ushort2*>(hlane + (size_t)sj * OF);
                acc[0] = fmaf(al, bf2f(hv.x), acc[0]);
                acc[1] = fmaf(al, bf2f(hv.y), acc[1]);
            }
        }
    } else {
        float mx[H], sm[H];
#pragma unroll
        for (int t = 0; t < H; ++t) mx[t] = -INFINITY;
        for (int e = e0 + ll; e < e1; e += 32) {
            int s = ssrc[e];
            float asv[H];
            if constexpr (H == 4) {
                float4 v = *reinterpret_cast<const float4*>(a_s + (size_t)s * 4);
                asv[0] = v.x; asv[1] = v.y; asv[2] = v.z; asv[3] = v.w;
            } else asv[0] = a_s[s];
#pragma unroll
            for (int t = 0; t < H; ++t) mx[t] = fmaxf(mx[t], lrelu(asv[t] + ad[t]));
        }
#pragma unroll
        for (int t = 0; t < H; ++t)
#pragma unroll
            for (int o = 1; o < 32; o <<= 1) mx[t] = fmaxf(mx[t], __shfl_xor(mx[t], o, 64));
#pragma unroll
        for (int t = 0; t < H; ++t) sm[t] = 0.f;
        for (int e = e0 + ll; e < e1; e += 32) {
            int s = ssrc[e];
            float asv[H];
            if constexpr (H == 4) {
                float4 v = *reinterpret_cast<const float4*>(a_s + (size_t)s * 4);
                asv[0] = v.x; asv[1] = v.y; asv[2] = v.z; asv[3] = v.w;
            } else asv[0] = a_s[s];
#pragma unroll
            for (int t = 0; t < H; ++t) sm[t] += __expf(lrelu(asv[t] + ad[t]) - mx[t]);
        }
#pragma unroll
        for (int t = 0; t < H; ++t)
#pragma unroll
            for (int o = 1; o < 32; o <<= 1) sm[t] += __shfl_xor(sm[t], o, 64);

        float mxl = mx[0], sml = sm[0], adl = ad[0];
#pragma unroll
        for (int t = 1; t < H; ++t) {
            mxl = (hd == t) ? mx[t] : mxl;
            sml = (hd == t) ? sm[t] : sml;
            adl = (hd == t) ? ad[t] : adl;
        }
        const float invl = 1.f / (sml + 1e-16f);
        const ushort* hlane = hf + (size_t)ll * V;
        for (int e = e0; e < e1; ++e) {
            int s0 = ssrc[e];
            float al0 = __expf(lrelu(a_s[(size_t)s0 * H + hd] + adl) - mxl) * invl;
            if constexpr (V == 8) {
                short8 hv = *reinterpret_cast<const short8*>(hlane + (size_t)s0 * OF);
#pragma unroll
                for (int i = 0; i < 8; ++i)
                    acc[i] = fmaf(al0, bf2f((ushort)hv[i]), acc[i]);
            } else {
                ushort2 hv = *reinterpret_cast<const ushort2*>(hlane + (size_t)s0 * OF);
                acc[0] = fmaf(al0, bf2f(hv.x), acc[0]);
                acc[1] = fmaf(al0, bf2f(hv.y), acc[1]);
            }
        }
    }

    // epilogue: + bias, ELU -> y (bf16 out + LDS stage for BN stats)
    float res[V];
#pragma unroll
    for (int i = 0; i < V; ++i) {
        float t = acc[i] + bias[ll * V + i];
        res[i] = t > 0.f ? t : (expf(t) - 1.f);
    }
    if constexpr (V == 8) {
        short8 yv = {(short)f2bf(res[0]), (short)f2bf(res[1]), (short)f2bf(res[2]), (short)f2bf(res[3]),
                     (short)f2bf(res[4]), (short)f2bf(res[5]), (short)f2bf(res[6]), (short)f2bf(res[7])};
        *reinterpret_cast<short8*>(&ybuf[(size_t)dst * OF + ll * 8]) = yv;
        *reinterpret_cast<f32x4*>(&ysh[dl][ll * 8 + 0]) = f32x4{res[0], res[1], res[2], res[3]};
        *reinterpret_cast<f32x4*>(&ysh[dl][ll * 8 + 4]) = f32x4{res[4], res[5], res[6], res[7]};
    } else {
        ushort2 yv = {f2bf(res[0]), f2bf(res[1])};
        *reinterpret_cast<ushort2*>(&ybuf[(size_t)dst * OF + ll * 2]) = yv;
        ysh[dl][ll * 2 + 0] = res[0];
        ysh[dl][ll * 2 + 1] = res[1];
    }
    __syncthreads();
    if (tid < OF) {
        float s = 0.f, s2 = 0.f;
#pragma unroll
        for (int d = 0; d < 8; ++d) {
            float v = ysh[d][tid];
            s += v;
            s2 = fmaf(v, v, s2);
        }
        int slot = blockIdx.x & 7;
        atomicAdd(&bnsum[(size_t)slot * 2 * OF + tid], s);
        atomicAdd(&bnsum[(size_t)slot * 2 * OF + OF + tid], s2);
    }
}

// ---------------- edge bucketing ----------------
__global__ void edge_count(const int* __restrict__ ei, int* __restrict__ counts)
{
    int i = blockIdx.x * blockDim.x + threadIdx.x;
    if (i >= E_TOT) return;
    int dst = (i < NUM_E) ? ei[NUM_E + i] : (i - NUM_E);
    atomicAdd(&counts[dst], 1);
}

__global__ void edge_scatter(const int* __restrict__ ei, int* __restrict__ cursor,
                             int* __restrict__ ssrc)
{
    int i = blockIdx.x * blockDim.x + threadIdx.x;
    if (i >= E_TOT) return;
    int src, dst;
    if (i < NUM_E) { src = ei[i]; dst = ei[NUM_E + i]; }
    else           { src = dst = i - NUM_E; }
    int pos = atomicAdd(&cursor[dst], 1);
    ssrc[pos] = src;
}

// ---------------- scan ----------------
__global__ void scan_block(const int* __restrict__ in, int n,
                           int* __restrict__ incl, int* __restrict__ bsum)
{
    __shared__ int sh[256];
    int tid = threadIdx.x;
    int i = blockIdx.x * 256 + tid;
    int v = (i < n) ? in[i] : 0;
    sh[tid] = v;
    __syncthreads();
    for (int o = 1; o < 256; o <<= 1) {
        int t = (tid >= o) ? sh[tid - o] : 0;
        __syncthreads();
        sh[tid] += t;
        __syncthreads();
    }
    if (i < n) incl[i] = sh[tid];
    if (tid == 255) bsum[blockIdx.x] = sh[255];
}

__global__ void scan_final(const int* __restrict__ incl, const int* __restrict__ in,
                           const int* __restrict__ bsum, int n,
                           int* __restrict__ offs, int* __restrict__ cursor)
{
    __shared__ int sh[256];
    const int tid = threadIdx.x;
    const int bi = blockIdx.x;
    sh[tid] = (tid < bi) ? bsum[tid] : 0;
    __syncthreads();
    for (int o = 128; o > 0; o >>= 1) {
        if (tid < o) sh[tid] += sh[tid + o];
        __syncthreads();
    }
    const int pref = sh[0];
    int i = bi * 256 + tid;
    if (i >= n) return;
    int excl = incl[i] - in[i] + pref;
    offs[i] = excl;
    cursor[i] = excl;
    if (i == n - 1) offs[n] = incl[i] + pref;
}

// ---------------- BN finalize: reduce 8 slots -> scale/shift; self-zero bnsum ----------------
template<int OF>
__global__ void bn_finalize(float* __restrict__ bnsum, const float* __restrict__ gamma,
                            const float* __restrict__ beta, float* __restrict__ ss)
{
    int c = threadIdx.x;
    if (c >= OF) return;
    float s = 0.f, s2 = 0.f;
#pragma unroll
    for (int slot = 0; slot < 8; ++slot) {
        s += bnsum[(size_t)slot * 2 * OF + c];
        s2 += bnsum[(size_t)slot * 2 * OF + OF + c];
        bnsum[(size_t)slot * 2 * OF + c] = 0.f;
        bnsum[(size_t)slot * 2 * OF + OF + c] = 0.f;
    }
    float mean = s / (float)N_NODES;
    float var = s2 / (float)N_NODES - mean * mean;
    float inv = rsqrtf(var + EPS_BN);
    float sc = inv * gamma[c];
    ss[c] = sc;
    ss[OF + c] = beta[c] - mean * sc;
}

// ---------------- BN apply from y(bf16) -> xs fp32 + fused pooling (R8-proven 2-col variant) ----------------
template<int OF>
__global__ __launch_bounds__(256)
void bn_apply_pool(const ushort* __restrict__ y, float* __restrict__ xs, int ldx,
                   const float* __restrict__ ss,
                   const int* __restrict__ batch, float* __restrict__ pool, int poff)
{
    const int tid = threadIdx.x;
    constexpr int CP = OF / 2;        // column pairs per row: 128 or 32
    constexpr int RS = 256 / CP;      // parallel row lanes: 2 or 8
    const int c = (tid % CP) * 2;
    const int rsub = tid / CP;
    const int r0 = blockIdx.x * 16;
    const float sc0 = ss[c], sh0 = ss[OF + c];
    const float sc1 = ss[c + 1], sh1 = ss[OF + c + 1];
    float ps0 = 0.f, ps1 = 0.f;
    int curg = batch[r0 + rsub];
#pragma unroll
    for (int i = 0; i < 16 / RS; ++i) {
        int r = r0 + rsub + i * RS;
        int g = batch[r];
        if (g != curg) {
            atomicAdd(&pool[(size_t)curg * XS_COLS + poff + c], ps0);
            atomicAdd(&pool[(size_t)curg * XS_COLS + poff + c + 1], ps1);
            ps0 = ps1 = 0.f; curg = g;
        }
        ushort2 hv = *reinterpret_cast<const ushort2*>(y + (size_t)r * OF + c);
        float v0 = fmaf(bf2f(hv.x), sc0, sh0);
        float v1 = fmaf(bf2f(hv.y), sc1, sh1);
        float2 vv = {v0, v1};
        *reinterpret_cast<float2*>(&xs[(size_t)r * ldx + c]) = vv;
        ps0 += v0; ps1 += v1;
    }
    atomicAdd(&pool[(size_t)curg * XS_COLS + poff + c], ps0);
    atomicAdd(&pool[(size_t)curg * XS_COLS + poff + c + 1], ps1);
}

extern "C" void kernel_launch(void* const* d_in, const int* in_sizes, int n_in,
                              void* d_out, int out_size, void* d_ws, size_t ws_size,
                              hipStream_t stream)
{
    const float* x     = (const float*)d_in[0];
    const int*   ei    = (const int*)d_in[1];
    const int*   batch = (const int*)d_in[2];
    const float* W[3]    = {(const float*)d_in[3],  (const float*)d_in[9],  (const float*)d_in[15]};
    const float* asrc[3] = {(const float*)d_in[4],  (const float*)d_in[10], (const float*)d_in[16]};
    const float* adst[3] = {(const float*)d_in[5],  (const float*)d_in[11], (const float*)d_in[17]};
    const float* bia[3]  = {(const float*)d_in[6],  (const float*)d_in[12], (const float*)d_in[18]};
    const float* gam[3]  = {(const float*)d_in[7],  (const float*)d_in[13], (const float*)d_in[19]};
    const float* bet[3]  = {(const float*)d_in[8],  (const float*)d_in[14], (const float*)d_in[20]};

    char* wp = (char*)d_ws;
    auto alloc = [&](size_t bytes) -> void* {
        void* p = (void*)wp;
        wp += (bytes + 255) & ~(size_t)255;
        return p;
    };
    ushort* hbf   = (ushort*)alloc((size_t)N_NODES * 256 * 2);
    ushort* ybuf  = (ushort*)alloc((size_t)M_PAD * 256 * 2);
    float*  a_s   = (float*)alloc((size_t)N_NODES * 4 * 4);
    float*  a_d   = (float*)alloc((size_t)N_NODES * 4 * 4);
    int*    counts = (int*)alloc((size_t)N_NODES * 4);
    int*    offs   = (int*)alloc((size_t)(N_NODES + 1) * 4);
    int*    cursor = (int*)alloc((size_t)N_NODES * 4);
    int*    incl   = (int*)alloc((size_t)N_NODES * 4);
    int*    bsums  = (int*)alloc(1024);
    int*    ssrc   = (int*)alloc((size_t)E_TOT * 4);
    float*  bnsum  = (float*)alloc((size_t)8 * 2 * 256 * 4);
    float*  bnss   = (float*)alloc(2 * 256 * 4);
    ushort* Wt0    = (ushort*)alloc(256 * 128 * 2);
    ushort* Wt1    = (ushort*)alloc(256 * 256 * 2);
    ushort* Wt2    = (ushort*)alloc(64 * 256 * 2);

    float* pool = (float*)d_out;                    // [128, 576]
    float* xs   = pool + (size_t)NGRAPH * XS_COLS;  // [50000, 576]

    // ---- setup ----
    hipMemsetAsync(counts, 0, (size_t)N_NODES * 4, stream);
    hipMemsetAsync(pool, 0, (size_t)NGRAPH * XS_COLS * 4, stream);
    hipMemsetAsync(bnsum, 0, (size_t)8 * 2 * 256 * 4, stream);
    edge_count<<<ceil_div(E_TOT, 256), 256, 0, stream>>>(ei, counts);
    const int NSB = ceil_div(N_NODES, 256);
    scan_block<<<NSB, 256, 0, stream>>>(counts, N_NODES, incl, bsums);
    scan_final<<<NSB, 256, 0, stream>>>(incl, counts, bsums, N_NODES, offs, cursor);
    edge_scatter<<<ceil_div(E_TOT, 256), 256, 0, stream>>>(ei, cursor, ssrc);
    const int PREP_ITEMS = 256 * 128 + 256 * 256 + 64 * 256;
    prep_w<<<ceil_div(PREP_ITEMS, 256), 256, 0, stream>>>(W[0], W[1], W[2], Wt0, Wt1, Wt2);

    const int NW2 = ceil_div(N_NODES, 8);   // 6250 (exact)
    const int NMB = ceil_div(N_NODES, 128);
    const int NBA = N_NODES / 16;           // 3125 (exact)

    // ---------------- layer 0: 128 -> 4x64 concat (256) ----------------
    {
        gemm_bf16_w<0><<<NMB, 512, 0, stream>>>(x, 128, nullptr, nullptr, Wt0, 128, hbf, N_NODES, 128,
                                                asrc[0], adst[0], a_s, a_d);
        gat_fused2<4, 64><<<NW2, 256, 0, stream>>>(offs, ssrc, a_s, a_d, hbf, bia[0], ybuf, bnsum);
        bn_finalize<256><<<1, 256, 0, stream>>>(bnsum, gam[0], bet[0], bnss);
        bn_apply_pool<256><<<NBA, 256, 0, stream>>>(ybuf, xs + 0, XS_COLS, bnss, batch, pool, 0);
    }
    // ---------------- layer 1: 256 -> 4x64 concat (256); BN applied in GEMM staging ----------------
    {
        gemm_bf16_w<2><<<NMB, 512, 0, stream>>>(ybuf, 256, bnss, bnss + 256, Wt1, 256, hbf, N_NODES, 256,
                                                asrc[1], adst[1], a_s, a_d);
        gat_fused2<4, 64><<<NW2, 256, 0, stream>>>(offs, ssrc, a_s, a_d, hbf, bia[1], ybuf, bnsum);
        bn_finalize<256><<<1, 256, 0, stream>>>(bnsum, gam[1], bet[1], bnss);
        bn_apply_pool<256><<<NBA, 256, 0, stream>>>(ybuf, xs + 256, XS_COLS, bnss, batch, pool, 256);
    }
    // ---------------- layer 2: 256 -> 1x64; BN applied in GEMM staging ----------------
    {
        gemm_bf16_n<<<NMB, 256, 0, stream>>>(ybuf, 256, bnss, bnss + 256, Wt2, 256, hbf, 64, N_NODES, 256,
                                             asrc[2], adst[2], a_s, a_d);
        gat_fused2<1, 64><<<NW2, 256, 0, stream>>>(offs, ssrc, a_s, a_d, hbf, bia[2], ybuf, bnsum);
        bn_finalize<64><<<1, 64, 0, stream>>>(bnsum, gam[2], bet[2], bnss);
        bn_apply_pool<64><<<NBA, 256, 0, stream>>>(ybuf, xs + 512, XS_COLS, bnss, batch, pool, 512);
    }
}